// Round 1
// baseline (1055.418 us; speedup 1.0000x reference)
//
#include <hip/hip_runtime.h>

#define CH 256
#define NHEAD 4
#define HD 64
#define SP 4096
#define NB 2

// ---------------------------------------------------------------------------
// Kernel 1: GroupNorm stats. One block per (b, group). Produces per-channel
// affine a[c], b[c] such that hn = a*x + b.
// ---------------------------------------------------------------------------
__global__ __launch_bounds__(256) void gn_stats_kernel(
    const float* __restrict__ x, const float* __restrict__ gamma,
    const float* __restrict__ beta, float* __restrict__ a_out,
    float* __restrict__ b_out)
{
    int bg = blockIdx.x;            // b*32 + g
    int b = bg >> 5, g = bg & 31;
    const float4* xp = (const float4*)(x + ((size_t)b * CH + g * 8) * SP);
    int tid = threadIdx.x;
    float s = 0.f, ss = 0.f;
    // 8 channels * 4096 = 32768 floats = 8192 float4
    for (int i = tid; i < 8192; i += 256) {
        float4 u = xp[i];
        s  += (u.x + u.y) + (u.z + u.w);
        ss += (u.x * u.x + u.y * u.y) + (u.z * u.z + u.w * u.w);
    }
#pragma unroll
    for (int off = 32; off > 0; off >>= 1) {
        s  += __shfl_down(s, off);
        ss += __shfl_down(ss, off);
    }
    __shared__ float ws_s[4], ws_q[4], stat[2];
    int w = tid >> 6;
    if ((tid & 63) == 0) { ws_s[w] = s; ws_q[w] = ss; }
    __syncthreads();
    if (tid == 0) {
        float st = ws_s[0] + ws_s[1] + ws_s[2] + ws_s[3];
        float qt = ws_q[0] + ws_q[1] + ws_q[2] + ws_q[3];
        float mu = st * (1.f / 32768.f);
        float var = qt * (1.f / 32768.f) - mu * mu;
        float rs = rsqrtf(var + 1e-5f);
        stat[0] = mu; stat[1] = rs;
    }
    __syncthreads();
    if (tid < 8) {
        int c = g * 8 + tid;
        float mu = stat[0], rs = stat[1];
        float ga = gamma[c];
        a_out[b * CH + c] = rs * ga;
        b_out[b * CH + c] = beta[c] - mu * rs * ga;
    }
}

// ---------------------------------------------------------------------------
// Kernel 2: Q/K/V projection GEMM, GroupNorm fused into the X staging.
// out[o][s] = bias[o] + sum_c W[o][c] * (a[c]*x[c][s] + b[c])
// Output layout: [b][n][d][s]  (o = d*4 + n), s contiguous.
// Block: 64 o x 64 s, K-steps of 16. 256 threads, 4x4 per thread.
// ---------------------------------------------------------------------------
__global__ __launch_bounds__(256) void qkv_kernel(
    const float* __restrict__ x,
    const float* __restrict__ wq, const float* __restrict__ bq,
    const float* __restrict__ wk, const float* __restrict__ bk,
    const float* __restrict__ wv, const float* __restrict__ bv,
    const float* __restrict__ aff_a, const float* __restrict__ aff_b,
    float* __restrict__ qo, float* __restrict__ ko, float* __restrict__ vo)
{
    int zz = blockIdx.z;            // b*3 + p
    int b = zz / 3, p = zz % 3;
    const float* W; const float* bias; float* outp;
    if (p == 0)      { W = wq; bias = bq; outp = qo; }
    else if (p == 1) { W = wk; bias = bk; outp = ko; }
    else             { W = wv; bias = bv; outp = vo; }

    int s0 = blockIdx.x * 64;
    int o0 = blockIdx.y * 64;
    int tid = threadIdx.x;
    int tx = tid & 15, ty = tid >> 4;

    __shared__ float Wt[16][68];   // [kk][o_local]  (W transposed)
    __shared__ float Xs[16][68];   // [kk][s_local]  (normalized x)

    const float* xb  = x + (size_t)b * CH * SP;
    const float* av  = aff_a + b * CH;
    const float* bv2 = aff_b + b * CH;

    float acc[4][4] = {{0.f, 0.f, 0.f, 0.f}, {0.f, 0.f, 0.f, 0.f},
                       {0.f, 0.f, 0.f, 0.f}, {0.f, 0.f, 0.f, 0.f}};

    int wo = tid >> 2, wc = tid & 3;    // W staging: o_local, c-quad
    int xr = tid >> 4, xc = tid & 15;   // X staging: c-row, s-quad

    for (int c0 = 0; c0 < CH; c0 += 16) {
        float4 w4 = *(const float4*)&W[(size_t)(o0 + wo) * CH + c0 + 4 * wc];
        int c = c0 + xr;
        float4 xv = *(const float4*)&xb[(size_t)c * SP + s0 + 4 * xc];
        float aa = av[c], bb = bv2[c];
        __syncthreads();    // previous iteration's readers done
        Wt[4 * wc + 0][wo] = w4.x;
        Wt[4 * wc + 1][wo] = w4.y;
        Wt[4 * wc + 2][wo] = w4.z;
        Wt[4 * wc + 3][wo] = w4.w;
        float4 xn;
        xn.x = fmaf(aa, xv.x, bb); xn.y = fmaf(aa, xv.y, bb);
        xn.z = fmaf(aa, xv.z, bb); xn.w = fmaf(aa, xv.w, bb);
        *(float4*)&Xs[xr][4 * xc] = xn;
        __syncthreads();
#pragma unroll
        for (int kk = 0; kk < 16; kk++) {
            float4 wv4 = *(const float4*)&Wt[kk][4 * ty];
            float4 xv4 = *(const float4*)&Xs[kk][4 * tx];
            float wa[4] = {wv4.x, wv4.y, wv4.z, wv4.w};
            float xa[4] = {xv4.x, xv4.y, xv4.z, xv4.w};
#pragma unroll
            for (int i = 0; i < 4; i++)
#pragma unroll
                for (int j = 0; j < 4; j++)
                    acc[i][j] = fmaf(wa[i], xa[j], acc[i][j]);
        }
    }

    int dbase = (o0 >> 2) + ty;         // o = o0+4*ty+i -> d = o>>2, n = i
    size_t scol = (size_t)s0 + 4 * tx;
#pragma unroll
    for (int i = 0; i < 4; i++) {
        int o = o0 + 4 * ty + i;
        float bi = bias[o];
        float4 r;
        r.x = acc[i][0] + bi; r.y = acc[i][1] + bi;
        r.z = acc[i][2] + bi; r.w = acc[i][3] + bi;
        *(float4*)&outp[((size_t)(b * NHEAD + i) * HD + dbase) * SP + scol] = r;
    }
}

// ---------------------------------------------------------------------------
// Kernel 3: flash attention, fp32. One block per (z = b*4+n, 64-row Q tile).
// Q/K/V layout [z][d][s]. Online softmax; P round-trips through LDS.
// V and P tiles use XOR col-quad swizzle so hot-loop b128 reads are
// conflict-free. grid.x = z so each XCD's L2 keeps one z's K/V (2 MB).
// ---------------------------------------------------------------------------
__global__ __launch_bounds__(256) void attn_kernel(
    const float* __restrict__ qb, const float* __restrict__ kb,
    const float* __restrict__ vb, float* __restrict__ ob)
{
    int z = blockIdx.x;             // 0..7
    int sq0 = blockIdx.y * 64;
    const float* qz = qb + (size_t)z * HD * SP;
    const float* kz = kb + (size_t)z * HD * SP;
    const float* vz = vb + (size_t)z * HD * SP;
    float*       oz = ob + (size_t)z * HD * SP;

    int tid = threadIdx.x;
    int tx = tid & 15, ty = tid >> 4;

    __shared__ float Qs[64][64];    // [d][r]
    __shared__ float Ks[64][64];    // [d][c]
    __shared__ float Vs[64][64];    // [d][j], col-quad ^= (d>>2)
    __shared__ float Ps[64][64];    // [r][j], col-quad ^= (r>>2); rows wave-private

    // load Q tile (scale 1/8 folded in here)
#pragma unroll
    for (int i = 0; i < 4; i++) {
        int idx = tid + 256 * i;
        int d = idx >> 4, r4 = idx & 15;
        float4 v4 = *(const float4*)&qz[(size_t)d * SP + sq0 + 4 * r4];
        v4.x *= 0.125f; v4.y *= 0.125f; v4.z *= 0.125f; v4.w *= 0.125f;
        *(float4*)&Qs[d][4 * r4] = v4;
    }

    float m_i[4], l_i[4], oa[4][4];
#pragma unroll
    for (int i = 0; i < 4; i++) {
        m_i[i] = -1e30f; l_i[i] = 0.f;
#pragma unroll
        for (int j = 0; j < 4; j++) oa[i][j] = 0.f;
    }

    for (int kt = 0; kt < SP; kt += 64) {
        // prefetch K/V tile into registers while previous tile computes
        float4 kv[4], vv[4];
#pragma unroll
        for (int i = 0; i < 4; i++) {
            int idx = tid + 256 * i;
            int d = idx >> 4, r4 = idx & 15;
            kv[i] = *(const float4*)&kz[(size_t)d * SP + kt + 4 * r4];
            vv[i] = *(const float4*)&vz[(size_t)d * SP + kt + 4 * r4];
        }
        __syncthreads();    // previous tile's LDS readers done (and Q store on iter 0)
#pragma unroll
        for (int i = 0; i < 4; i++) {
            int idx = tid + 256 * i;
            int d = idx >> 4, r4 = idx & 15;
            *(float4*)&Ks[d][4 * r4] = kv[i];
            *(float4*)&Vs[d][4 * (r4 ^ (d >> 2))] = vv[i];
        }
        __syncthreads();

        // scores: sc[i][j] = sum_d Q[4ty+i][d] * K[4tx+j][d]   (pre-scaled)
        float sc[4][4] = {{0.f, 0.f, 0.f, 0.f}, {0.f, 0.f, 0.f, 0.f},
                          {0.f, 0.f, 0.f, 0.f}, {0.f, 0.f, 0.f, 0.f}};
#pragma unroll 8
        for (int kk = 0; kk < 64; kk++) {
            float4 q4 = *(const float4*)&Qs[kk][4 * ty];
            float4 k4 = *(const float4*)&Ks[kk][4 * tx];
            float qa[4] = {q4.x, q4.y, q4.z, q4.w};
            float ka[4] = {k4.x, k4.y, k4.z, k4.w};
#pragma unroll
            for (int i = 0; i < 4; i++)
#pragma unroll
                for (int j = 0; j < 4; j++)
                    sc[i][j] = fmaf(qa[i], ka[j], sc[i][j]);
        }

        // online softmax per Q-row (16 lanes of a row group share one wave)
#pragma unroll
        for (int i = 0; i < 4; i++) {
            float mx = fmaxf(fmaxf(sc[i][0], sc[i][1]), fmaxf(sc[i][2], sc[i][3]));
#pragma unroll
            for (int msk = 1; msk < 16; msk <<= 1)
                mx = fmaxf(mx, __shfl_xor(mx, msk));
            float mnew = fmaxf(m_i[i], mx);
            float al = __expf(m_i[i] - mnew);
            m_i[i] = mnew;
            float rs = 0.f;
#pragma unroll
            for (int j = 0; j < 4; j++) {
                sc[i][j] = __expf(sc[i][j] - mnew);
                rs += sc[i][j];
            }
#pragma unroll
            for (int msk = 1; msk < 16; msk <<= 1)
                rs += __shfl_xor(rs, msk);
            l_i[i] = l_i[i] * al + rs;
#pragma unroll
            for (int j = 0; j < 4; j++) oa[i][j] *= al;
            // P row 4ty+i is written and later read only by this wave's ty-group
            *(float4*)&Ps[4 * ty + i][4 * (tx ^ ty)] =
                make_float4(sc[i][0], sc[i][1], sc[i][2], sc[i][3]);
        }
        // no barrier: Ps rows are wave-private; DS ops are in-order per wave

        // PV: oa[i][j] += sum_jj P[4ty+i][jj] * V[jj][4tx+j]
#pragma unroll
        for (int jc = 0; jc < 16; jc++) {
            float4 p4[4], v4[4];
#pragma unroll
            for (int i = 0; i < 4; i++)
                p4[i] = *(const float4*)&Ps[4 * ty + i][4 * (jc ^ ty)];
#pragma unroll
            for (int j = 0; j < 4; j++)
                v4[j] = *(const float4*)&Vs[4 * tx + j][4 * (jc ^ tx)];
#pragma unroll
            for (int i = 0; i < 4; i++)
#pragma unroll
                for (int j = 0; j < 4; j++)
                    oa[i][j] += p4[i].x * v4[j].x + p4[i].y * v4[j].y +
                                p4[i].z * v4[j].z + p4[i].w * v4[j].w;
        }
    }

    float invl[4];
#pragma unroll
    for (int i = 0; i < 4; i++) invl[i] = 1.f / l_i[i];
    // store O in [z][d][s]
#pragma unroll
    for (int j = 0; j < 4; j++) {
        float4 r;
        r.x = oa[0][j] * invl[0]; r.y = oa[1][j] * invl[1];
        r.z = oa[2][j] * invl[2]; r.w = oa[3][j] * invl[3];
        *(float4*)&oz[(size_t)(4 * tx + j) * SP + sq0 + 4 * ty] = r;
    }
}

// ---------------------------------------------------------------------------
// Kernel 4: output projection + residual.
// out[c][s] = x[c][s] + bp[c] + sum_o wp[c][o] * O[o][s],  o=(d*4+n)
// ---------------------------------------------------------------------------
__global__ __launch_bounds__(256) void proj_kernel(
    const float* __restrict__ obuf, const float* __restrict__ wp,
    const float* __restrict__ bp, const float* __restrict__ x,
    float* __restrict__ out)
{
    int b = blockIdx.z;
    int s0 = blockIdx.x * 64;
    int c0 = blockIdx.y * 64;
    int tid = threadIdx.x;
    int tx = tid & 15, ty = tid >> 4;

    __shared__ float Wt[16][68];
    __shared__ float Xs[16][68];

    float acc[4][4] = {{0.f, 0.f, 0.f, 0.f}, {0.f, 0.f, 0.f, 0.f},
                       {0.f, 0.f, 0.f, 0.f}, {0.f, 0.f, 0.f, 0.f}};

    int wo = tid >> 2, wc = tid & 3;
    int xr = tid >> 4, xc = tid & 15;

    const float* ob_b = obuf + (size_t)b * NHEAD * HD * SP;

    for (int k0 = 0; k0 < CH; k0 += 16) {
        float4 w4 = *(const float4*)&wp[(size_t)(c0 + wo) * CH + k0 + 4 * wc];
        int o = k0 + xr;
        const float* orow = ob_b + ((size_t)(o & 3) * HD + (o >> 2)) * SP;
        float4 xv = *(const float4*)&orow[s0 + 4 * xc];
        __syncthreads();
        Wt[4 * wc + 0][wo] = w4.x;
        Wt[4 * wc + 1][wo] = w4.y;
        Wt[4 * wc + 2][wo] = w4.z;
        Wt[4 * wc + 3][wo] = w4.w;
        *(float4*)&Xs[xr][4 * xc] = xv;
        __syncthreads();
#pragma unroll
        for (int kk = 0; kk < 16; kk++) {
            float4 wv4 = *(const float4*)&Wt[kk][4 * ty];
            float4 xv4 = *(const float4*)&Xs[kk][4 * tx];
            float wa[4] = {wv4.x, wv4.y, wv4.z, wv4.w};
            float xa[4] = {xv4.x, xv4.y, xv4.z, xv4.w};
#pragma unroll
            for (int i = 0; i < 4; i++)
#pragma unroll
                for (int j = 0; j < 4; j++)
                    acc[i][j] = fmaf(wa[i], xa[j], acc[i][j]);
        }
    }

#pragma unroll
    for (int i = 0; i < 4; i++) {
        int c = c0 + 4 * ty + i;
        float bi = bp[c];
        size_t idx = ((size_t)b * CH + c) * SP + s0 + 4 * tx;
        float4 xr4 = *(const float4*)&x[idx];
        float4 r;
        r.x = acc[i][0] + bi + xr4.x; r.y = acc[i][1] + bi + xr4.y;
        r.z = acc[i][2] + bi + xr4.z; r.w = acc[i][3] + bi + xr4.w;
        *(float4*)&out[idx] = r;
    }
}

// ---------------------------------------------------------------------------
extern "C" void kernel_launch(void* const* d_in, const int* in_sizes, int n_in,
                              void* d_out, int out_size, void* d_ws, size_t ws_size,
                              hipStream_t stream)
{
    const float* x     = (const float*)d_in[0];
    const float* gamma = (const float*)d_in[1];
    const float* beta  = (const float*)d_in[2];
    const float* wq = (const float*)d_in[3]; const float* bq = (const float*)d_in[4];
    const float* wk = (const float*)d_in[5]; const float* bk = (const float*)d_in[6];
    const float* wv = (const float*)d_in[7]; const float* bv = (const float*)d_in[8];
    const float* wp = (const float*)d_in[9]; const float* bp = (const float*)d_in[10];
    float* out = (float*)d_out;

    // ws layout (floats): a[512] | b[512] | q | k | v | o   (each 2M floats)
    const size_t TEN = (size_t)NB * NHEAD * HD * SP;   // 2,097,152
    float* wsf   = (float*)d_ws;
    float* aff_a = wsf;
    float* aff_b = wsf + 512;
    float* qb    = wsf + 1024;
    float* kb    = qb + TEN;
    float* vb    = kb + TEN;
    float* obuf  = vb + TEN;

    gn_stats_kernel<<<dim3(64), dim3(256), 0, stream>>>(x, gamma, beta, aff_a, aff_b);
    qkv_kernel<<<dim3(64, 4, 6), dim3(256), 0, stream>>>(
        x, wq, bq, wk, bk, wv, bv, aff_a, aff_b, qb, kb, vb);
    attn_kernel<<<dim3(8, 64), dim3(256), 0, stream>>>(qb, kb, vb, obuf);
    proj_kernel<<<dim3(64, 4, 2), dim3(256), 0, stream>>>(obuf, wp, bp, x, out);
}

// Round 2
// 297.374 us; speedup vs baseline: 3.5491x; 3.5491x over previous
//
#include <hip/hip_runtime.h>

#define CH 256
#define NHEAD 4
#define HD 64
#define SP 4096
#define NB 2

typedef __attribute__((ext_vector_type(8))) short bf16x8;   // MFMA A/B frag (4 VGPR)
typedef __attribute__((ext_vector_type(4))) float f32x4;    // MFMA C/D frag

// fast float->bf16 (round-half-up; inputs are well-scaled, no inf/nan)
__device__ inline unsigned short b16(float f) {
    unsigned u = __float_as_uint(f);
    return (unsigned short)((u + 0x8000u) >> 16);
}
// pack two floats -> (bf16(hi)<<16)|bf16(lo)
__device__ inline unsigned bpack(float lo, float hi) {
    unsigned ul = __float_as_uint(lo), uh = __float_as_uint(hi);
    return ((uh + 0x8000u) & 0xffff0000u) | ((ul + 0x8000u) >> 16);
}

// ---------------------------------------------------------------------------
// Kernel 1: GroupNorm stats -> per-channel affine a[c], b[c] (hn = a*x + b)
// ---------------------------------------------------------------------------
__global__ __launch_bounds__(256) void gn_stats_kernel(
    const float* __restrict__ x, const float* __restrict__ gamma,
    const float* __restrict__ beta, float* __restrict__ a_out,
    float* __restrict__ b_out)
{
    int bg = blockIdx.x;
    int b = bg >> 5, g = bg & 31;
    const float4* xp = (const float4*)(x + ((size_t)b * CH + g * 8) * SP);
    int tid = threadIdx.x;
    float s = 0.f, ss = 0.f;
    for (int i = tid; i < 8192; i += 256) {
        float4 u = xp[i];
        s  += (u.x + u.y) + (u.z + u.w);
        ss += (u.x * u.x + u.y * u.y) + (u.z * u.z + u.w * u.w);
    }
#pragma unroll
    for (int off = 32; off > 0; off >>= 1) {
        s  += __shfl_down(s, off);
        ss += __shfl_down(ss, off);
    }
    __shared__ float ws_s[4], ws_q[4], stat[2];
    int w = tid >> 6;
    if ((tid & 63) == 0) { ws_s[w] = s; ws_q[w] = ss; }
    __syncthreads();
    if (tid == 0) {
        float st = ws_s[0] + ws_s[1] + ws_s[2] + ws_s[3];
        float qt = ws_q[0] + ws_q[1] + ws_q[2] + ws_q[3];
        float mu = st * (1.f / 32768.f);
        float var = qt * (1.f / 32768.f) - mu * mu;
        float rs = rsqrtf(var + 1e-5f);
        stat[0] = mu; stat[1] = rs;
    }
    __syncthreads();
    if (tid < 8) {
        int c = g * 8 + tid;
        float mu = stat[0], rs = stat[1];
        float ga = gamma[c];
        a_out[b * CH + c] = rs * ga;
        b_out[b * CH + c] = beta[c] - mu * rs * ga;
    }
}

// ---------------------------------------------------------------------------
// Kernel 2: Q/K/V projection GEMM (GroupNorm fused into X staging).
// Outputs:  Q fp32 [z][d][s]   (z = b*4+n)
//           K^T bf16 [z][s][d] (via LDS transpose epilogue)
//           V  bf16 [z][d][s]
// ---------------------------------------------------------------------------
__global__ __launch_bounds__(256) void qkv_kernel(
    const float* __restrict__ x,
    const float* __restrict__ wq, const float* __restrict__ bq,
    const float* __restrict__ wk, const float* __restrict__ bk,
    const float* __restrict__ wv, const float* __restrict__ bv,
    const float* __restrict__ aff_a, const float* __restrict__ aff_b,
    float* __restrict__ qo, unsigned short* __restrict__ ko,
    unsigned short* __restrict__ vo)
{
    int zz = blockIdx.z;            // b*3 + p
    int b = zz / 3, p = zz % 3;
    const float* W; const float* bias;
    if (p == 0)      { W = wq; bias = bq; }
    else if (p == 1) { W = wk; bias = bk; }
    else             { W = wv; bias = bv; }

    int s0 = blockIdx.x * 64;
    int o0 = blockIdx.y * 64;
    int tid = threadIdx.x;
    int tx = tid & 15, ty = tid >> 4;

    __shared__ float Wt[16][68];   // [kk][o_local]
    __shared__ float Xs[16][68];   // [kk][s_local]
    __shared__ unsigned short Tb[64 * 20];  // K^T transpose staging (pitch 20)

    const float* xb  = x + (size_t)b * CH * SP;
    const float* av  = aff_a + b * CH;
    const float* bv2 = aff_b + b * CH;

    float acc[4][4] = {{0.f,0.f,0.f,0.f},{0.f,0.f,0.f,0.f},
                       {0.f,0.f,0.f,0.f},{0.f,0.f,0.f,0.f}};

    int wo = tid >> 2, wc = tid & 3;
    int xr = tid >> 4, xc = tid & 15;

    for (int c0 = 0; c0 < CH; c0 += 16) {
        float4 w4 = *(const float4*)&W[(size_t)(o0 + wo) * CH + c0 + 4 * wc];
        int c = c0 + xr;
        float4 xv = *(const float4*)&xb[(size_t)c * SP + s0 + 4 * xc];
        float aa = av[c], bb = bv2[c];
        __syncthreads();
        Wt[4 * wc + 0][wo] = w4.x;
        Wt[4 * wc + 1][wo] = w4.y;
        Wt[4 * wc + 2][wo] = w4.z;
        Wt[4 * wc + 3][wo] = w4.w;
        float4 xn;
        xn.x = fmaf(aa, xv.x, bb); xn.y = fmaf(aa, xv.y, bb);
        xn.z = fmaf(aa, xv.z, bb); xn.w = fmaf(aa, xv.w, bb);
        *(float4*)&Xs[xr][4 * xc] = xn;
        __syncthreads();
#pragma unroll
        for (int kk = 0; kk < 16; kk++) {
            float4 wv4 = *(const float4*)&Wt[kk][4 * ty];
            float4 xv4 = *(const float4*)&Xs[kk][4 * tx];
            float wa[4] = {wv4.x, wv4.y, wv4.z, wv4.w};
            float xa[4] = {xv4.x, xv4.y, xv4.z, xv4.w};
#pragma unroll
            for (int i = 0; i < 4; i++)
#pragma unroll
                for (int j = 0; j < 4; j++)
                    acc[i][j] = fmaf(wa[i], xa[j], acc[i][j]);
        }
    }

    int dbase = (o0 >> 2) + ty;   // d for this thread's rows (o = o0+4ty+i -> d=o>>2, n=i)
    if (p == 0) {
        // Q fp32 [z][d][s]
#pragma unroll
        for (int i = 0; i < 4; i++) {
            int o = o0 + 4 * ty + i;
            float bi = bias[o];
            float4 r;
            r.x = acc[i][0] + bi; r.y = acc[i][1] + bi;
            r.z = acc[i][2] + bi; r.w = acc[i][3] + bi;
            *(float4*)&qo[((size_t)(b * NHEAD + i) * HD + dbase) * SP + s0 + 4 * tx] = r;
        }
    } else if (p == 2) {
        // V bf16 [z][d][s]
#pragma unroll
        for (int i = 0; i < 4; i++) {
            int o = o0 + 4 * ty + i;
            float bi = bias[o];
            ushort4 r;
            r.x = b16(acc[i][0] + bi); r.y = b16(acc[i][1] + bi);
            r.z = b16(acc[i][2] + bi); r.w = b16(acc[i][3] + bi);
            *(ushort4*)&vo[((size_t)(b * NHEAD + i) * HD + dbase) * SP + s0 + 4 * tx] = r;
        }
    } else {
        // K^T bf16 [z][s][d] via LDS transpose (per head n=i)
        int d0 = o0 >> 2;
#pragma unroll
        for (int i = 0; i < 4; i++) {
            int o = o0 + 4 * ty + i;
            float bi = bias[o];
            __syncthreads();
#pragma unroll
            for (int j = 0; j < 4; j++)
                Tb[(4 * tx + j) * 20 + ty] = b16(acc[i][j] + bi);
            __syncthreads();
            int srow = tid >> 2, dq = (tid & 3) * 4;
            ushort4 r = *(const ushort4*)&Tb[srow * 20 + dq];
            *(ushort4*)&ko[((size_t)(b * NHEAD + i) * SP + s0 + srow) * HD + d0 + dq] = r;
        }
    }
}

// ---------------------------------------------------------------------------
// Kernel 3: MFMA flash attention (bf16 in, fp32 acc).
// Block = 4 waves x 32 q-rows = 128 q. Grid (z=8, qt=32) -> 256 blocks (1/CU),
// z == XCD (linear id mod 8) so each XCD's L2 keeps its K^T+V (1 MB).
//
// Orientation: S^T = K·Q^T via mfma(A=K-frag, B=Q-frag): lane ln=l&15 = q,
// key = kg*16 + 4*(l>>4) + reg. O = P·V^T-ish via mfma(A=P, B=V): C rows =
// q_local = 4*quad+reg, cols = d = dg*16+ln.
// All LDS frag data stored "frag-packed" (lane-major, 16B/lane) -> b128 reads
// are conflict-free. P transpose: per (qg,kg) one uint2 b64 write into a
// wave-private packed buffer (mapping derived from verified C/D + A layouts).
// ---------------------------------------------------------------------------
__global__ __launch_bounds__(256) void attn_kernel(
    const float* __restrict__ qb, const unsigned short* __restrict__ ktb,
    const unsigned short* __restrict__ vbb, float* __restrict__ ob)
{
    int z = blockIdx.x;
    int sq0 = blockIdx.y * 128;
    const float*          qz = qb  + (size_t)z * HD * SP;   // [d][s] fp32
    const unsigned short* kz = ktb + (size_t)z * SP * HD;   // [s][d] bf16
    const unsigned short* vz = vbb + (size_t)z * HD * SP;   // [d][s] bf16
    float* oz = ob + (size_t)z * HD * SP;

    int tid = threadIdx.x;
    int w = tid >> 6, l = tid & 63;
    int t = l >> 4, ln = l & 15;

    __shared__ __align__(16) unsigned short Kbuf[2][4096];  // 8 groups x 64 lanes x 8 bf16
    __shared__ __align__(16) unsigned short Vbuf[2][4096];
    __shared__ __align__(16) unsigned Pbuf[4][1024];        // per-wave P frags (4KB)

    // ---- Q B-frags (n=q=ln, k=d), scale 1/8 folded, kept in registers ----
    bf16x8 qf[2][2];   // [qg][ds]
#pragma unroll
    for (int qg = 0; qg < 2; qg++) {
        int q = sq0 + w * 32 + qg * 16 + ln;
#pragma unroll
        for (int ds = 0; ds < 2; ds++) {
            union { unsigned u[4]; bf16x8 v; } qu;
#pragma unroll
            for (int j2 = 0; j2 < 4; j2++) {
                int d = ds * 32 + t * 8 + 2 * j2;
                float f0 = qz[(size_t)d * SP + q] * 0.125f;
                float f1 = qz[(size_t)(d + 1) * SP + q] * 0.125f;
                qu.u[j2] = bpack(f0, f1);
            }
            qf[qg][ds] = qu.v;
        }
    }

    // ---- preload tile 0 (wave w stages groups 2w, 2w+1 of K and V) ----
    uint4 kr[2], vr[2];
#pragma unroll
    for (int gi = 0; gi < 2; gi++) {
        int g = 2 * w + gi;
        kr[gi] = *(const uint4*)(kz + (size_t)(0 + (g >> 1) * 16 + ln) * HD + (g & 1) * 32 + t * 8);
        vr[gi] = *(const uint4*)(vz + (size_t)((g >> 1) * 16 + ln) * SP + 0 + (g & 1) * 32 + t * 8);
    }
#pragma unroll
    for (int gi = 0; gi < 2; gi++) {
        int g = 2 * w + gi;
        *(uint4*)&Kbuf[0][g * 512 + l * 8] = kr[gi];
        *(uint4*)&Vbuf[0][g * 512 + l * 8] = vr[gi];
    }

    float m_i[2] = {-1e30f, -1e30f};
    float l_i[2] = {0.f, 0.f};
    f32x4 oacc[2][4];
#pragma unroll
    for (int qg = 0; qg < 2; qg++)
#pragma unroll
        for (int dg = 0; dg < 4; dg++)
            oacc[qg][dg] = (f32x4){0.f, 0.f, 0.f, 0.f};

    for (int kti = 0; kti < 64; kti++) {
        int cb = kti & 1;
        __syncthreads();   // buf[cb] ready; buf[1-cb] free for overwrite

        if (kti < 63) {    // issue next tile's global loads (overlap with compute)
            int kt = (kti + 1) * 64;
#pragma unroll
            for (int gi = 0; gi < 2; gi++) {
                int g = 2 * w + gi;
                kr[gi] = *(const uint4*)(kz + (size_t)(kt + (g >> 1) * 16 + ln) * HD + (g & 1) * 32 + t * 8);
                vr[gi] = *(const uint4*)(vz + (size_t)((g >> 1) * 16 + ln) * SP + kt + (g & 1) * 32 + t * 8);
            }
        }

        // ---- QK^T: sa[qg][kg], m=key, n=q ----
        f32x4 sa[2][4];
#pragma unroll
        for (int qg = 0; qg < 2; qg++)
#pragma unroll
            for (int kg = 0; kg < 4; kg++)
                sa[qg][kg] = (f32x4){0.f, 0.f, 0.f, 0.f};
#pragma unroll
        for (int ds = 0; ds < 2; ds++) {
#pragma unroll
            for (int kg = 0; kg < 4; kg++) {
                bf16x8 kf = *(const bf16x8*)&Kbuf[cb][(kg * 2 + ds) * 512 + l * 8];
#pragma unroll
                for (int qg = 0; qg < 2; qg++)
                    sa[qg][kg] = __builtin_amdgcn_mfma_f32_16x16x32_bf16(
                        kf, qf[qg][ds], sa[qg][kg], 0, 0, 0);
            }
        }

        // ---- online softmax (stats per lane-column q=ln) + P pack/store ----
#pragma unroll
        for (int qg = 0; qg < 2; qg++) {
            float mx = -1e30f;
#pragma unroll
            for (int kg = 0; kg < 4; kg++)
#pragma unroll
                for (int r = 0; r < 4; r++)
                    mx = fmaxf(mx, sa[qg][kg][r]);
            mx = fmaxf(mx, __shfl_xor(mx, 16));
            mx = fmaxf(mx, __shfl_xor(mx, 32));
            float mnew = fmaxf(m_i[qg], mx);
            float alpha = __expf(m_i[qg] - mnew);
            m_i[qg] = mnew;
            float rs = 0.f;
#pragma unroll
            for (int kg = 0; kg < 4; kg++)
#pragma unroll
                for (int r = 0; r < 4; r++) {
                    float pv = __expf(sa[qg][kg][r] - mnew);
                    sa[qg][kg][r] = pv;
                    rs += pv;
                }
            rs += __shfl_xor(rs, 16);
            rs += __shfl_xor(rs, 32);
            l_i[qg] = l_i[qg] * alpha + rs;

            // P value at (lane l, reg r) is P[q=qg*16+ln][key=kg*16+4t+r].
            // A-frag target (qg, ks=kg>>1): lane ln + 16*(2*(kg&1)+(t>>1)),
            // dwords d=2*(t&1)+{0,1} (derivation in session notes).
#pragma unroll
            for (int kg = 0; kg < 4; kg++) {
                unsigned p0 = bpack(sa[qg][kg][0], sa[qg][kg][1]);
                unsigned p1 = bpack(sa[qg][kg][2], sa[qg][kg][3]);
                int Lt = ln + 16 * (2 * (kg & 1) + (t >> 1));
                int ks = kg >> 1;
                unsigned* dst = &Pbuf[w][(((qg * 2 + ks) * 64 + Lt) << 2) + 2 * (t & 1)];
                *(uint2*)dst = make_uint2(p0, p1);
            }

            // rescale O rows (row r of O tile = q_local 4t+r; alpha lives at lane 4t+r)
            float ar[4];
#pragma unroll
            for (int r = 0; r < 4; r++) ar[r] = __shfl(alpha, 20 * t + r);
#pragma unroll
            for (int dg = 0; dg < 4; dg++)
#pragma unroll
                for (int r = 0; r < 4; r++)
                    oacc[qg][dg][r] *= ar[r];
        }

        // ---- P A-frags (wave-private, in-wave DS ordering, no barrier) ----
        bf16x8 pf[2][2];
#pragma unroll
        for (int qg = 0; qg < 2; qg++)
#pragma unroll
            for (int ks = 0; ks < 2; ks++)
                pf[qg][ks] = *(const bf16x8*)&Pbuf[w][((qg * 2 + ks) * 64 + l) * 4];

        // ---- PV: O[q][d] += P·V ----
#pragma unroll
        for (int ks = 0; ks < 2; ks++) {
#pragma unroll
            for (int dg = 0; dg < 4; dg++) {
                bf16x8 vf = *(const bf16x8*)&Vbuf[cb][(dg * 2 + ks) * 512 + l * 8];
#pragma unroll
                for (int qg = 0; qg < 2; qg++)
                    oacc[qg][dg] = __builtin_amdgcn_mfma_f32_16x16x32_bf16(
                        pf[qg][ks], vf, oacc[qg][dg], 0, 0, 0);
            }
        }

        // ---- land next tile into the other buffer (vmcnt wait hidden above) ----
        if (kti < 63) {
            int nb = 1 - cb;
#pragma unroll
            for (int gi = 0; gi < 2; gi++) {
                int g = 2 * w + gi;
                *(uint4*)&Kbuf[nb][g * 512 + l * 8] = kr[gi];
                *(uint4*)&Vbuf[nb][g * 512 + l * 8] = vr[gi];
            }
        }
    }

    // ---- epilogue: O / l, store [z][d][s] fp32 ----
#pragma unroll
    for (int qg = 0; qg < 2; qg++) {
        float linv = 1.f / l_i[qg];
        float ir[4];
#pragma unroll
        for (int r = 0; r < 4; r++) ir[r] = __shfl(linv, 20 * t + r);
#pragma unroll
        for (int dg = 0; dg < 4; dg++) {
            int d = dg * 16 + ln;
#pragma unroll
            for (int r = 0; r < 4; r++)
                oz[(size_t)d * SP + sq0 + w * 32 + qg * 16 + 4 * t + r] =
                    oacc[qg][dg][r] * ir[r];
        }
    }
}

// ---------------------------------------------------------------------------
// Kernel 4: output projection + residual (fp32, unchanged).
// ---------------------------------------------------------------------------
__global__ __launch_bounds__(256) void proj_kernel(
    const float* __restrict__ obuf, const float* __restrict__ wp,
    const float* __restrict__ bp, const float* __restrict__ x,
    float* __restrict__ out)
{
    int b = blockIdx.z;
    int s0 = blockIdx.x * 64;
    int c0 = blockIdx.y * 64;
    int tid = threadIdx.x;
    int tx = tid & 15, ty = tid >> 4;

    __shared__ float Wt[16][68];
    __shared__ float Xs[16][68];

    float acc[4][4] = {{0.f,0.f,0.f,0.f},{0.f,0.f,0.f,0.f},
                       {0.f,0.f,0.f,0.f},{0.f,0.f,0.f,0.f}};

    int wo = tid >> 2, wc = tid & 3;
    int xr = tid >> 4, xc = tid & 15;

    const float* ob_b = obuf + (size_t)b * NHEAD * HD * SP;

    for (int k0 = 0; k0 < CH; k0 += 16) {
        float4 w4 = *(const float4*)&wp[(size_t)(c0 + wo) * CH + k0 + 4 * wc];
        int o = k0 + xr;
        const float* orow = ob_b + ((size_t)(o & 3) * HD + (o >> 2)) * SP;
        float4 xv = *(const float4*)&orow[s0 + 4 * xc];
        __syncthreads();
        Wt[4 * wc + 0][wo] = w4.x;
        Wt[4 * wc + 1][wo] = w4.y;
        Wt[4 * wc + 2][wo] = w4.z;
        Wt[4 * wc + 3][wo] = w4.w;
        *(float4*)&Xs[xr][4 * xc] = xv;
        __syncthreads();
#pragma unroll
        for (int kk = 0; kk < 16; kk++) {
            float4 wv4 = *(const float4*)&Wt[kk][4 * ty];
            float4 xv4 = *(const float4*)&Xs[kk][4 * tx];
            float wa[4] = {wv4.x, wv4.y, wv4.z, wv4.w};
            float xa[4] = {xv4.x, xv4.y, xv4.z, xv4.w};
#pragma unroll
            for (int i = 0; i < 4; i++)
#pragma unroll
                for (int j = 0; j < 4; j++)
                    acc[i][j] = fmaf(wa[i], xa[j], acc[i][j]);
        }
    }

#pragma unroll
    for (int i = 0; i < 4; i++) {
        int c = c0 + 4 * ty + i;
        float bi = bp[c];
        size_t idx = ((size_t)b * CH + c) * SP + s0 + 4 * tx;
        float4 xr4 = *(const float4*)&x[idx];
        float4 r;
        r.x = acc[i][0] + bi + xr4.x; r.y = acc[i][1] + bi + xr4.y;
        r.z = acc[i][2] + bi + xr4.z; r.w = acc[i][3] + bi + xr4.w;
        *(float4*)&out[idx] = r;
    }
}

// ---------------------------------------------------------------------------
extern "C" void kernel_launch(void* const* d_in, const int* in_sizes, int n_in,
                              void* d_out, int out_size, void* d_ws, size_t ws_size,
                              hipStream_t stream)
{
    const float* x     = (const float*)d_in[0];
    const float* gamma = (const float*)d_in[1];
    const float* beta  = (const float*)d_in[2];
    const float* wq = (const float*)d_in[3]; const float* bq = (const float*)d_in[4];
    const float* wk = (const float*)d_in[5]; const float* bk = (const float*)d_in[6];
    const float* wv = (const float*)d_in[7]; const float* bv = (const float*)d_in[8];
    const float* wp = (const float*)d_in[9]; const float* bp = (const float*)d_in[10];
    float* out = (float*)d_out;

    // ws layout: aff_a[512] aff_b[512] | Q fp32 2M | K^T bf16 2M | V bf16 2M | O fp32 2M
    const size_t TEN = (size_t)NB * NHEAD * HD * SP;   // 2,097,152
    float* wsf   = (float*)d_ws;
    float* aff_a = wsf;
    float* aff_b = wsf + 512;
    float* qbuf  = wsf + 1024;
    unsigned short* ktb = (unsigned short*)(qbuf + TEN);
    unsigned short* vbb = ktb + TEN;
    float* obuf  = (float*)(vbb + TEN);

    gn_stats_kernel<<<dim3(64), dim3(256), 0, stream>>>(x, gamma, beta, aff_a, aff_b);
    qkv_kernel<<<dim3(64, 4, 6), dim3(256), 0, stream>>>(
        x, wq, bq, wk, bk, wv, bv, aff_a, aff_b, qbuf, ktb, vbb);
    attn_kernel<<<dim3(8, 32), dim3(256), 0, stream>>>(qbuf, ktb, vbb, obuf);
    proj_kernel<<<dim3(64, 4, 2), dim3(256), 0, stream>>>(obuf, wp, bp, x, out);
}

// Round 3
// 212.139 us; speedup vs baseline: 4.9751x; 1.4018x over previous
//
#include <hip/hip_runtime.h>

#define CH 256
#define NHEAD 4
#define HD 64
#define SP 4096
#define NB 2
#define SCALE_Q 0.125f

typedef __attribute__((ext_vector_type(8))) short bf16x8;   // MFMA A/B frag
typedef __attribute__((ext_vector_type(4))) float f32x4;    // MFMA C/D frag
typedef unsigned int u32;
typedef unsigned short u16;

// float->bf16, round-half-up (inputs well-scaled, no inf/nan)
__device__ inline u16 b16(float f) {
    u32 u = __float_as_uint(f);
    return (u16)((u + 0x8000u) >> 16);
}

// ---------------------------------------------------------------------------
// Kernel 1: GroupNorm stats -> per-channel affine a[c], b[c] (hn = a*x + b)
// ---------------------------------------------------------------------------
__global__ __launch_bounds__(256) void gn_stats_kernel(
    const float* __restrict__ x, const float* __restrict__ gamma,
    const float* __restrict__ beta, float* __restrict__ a_out,
    float* __restrict__ b_out)
{
    int bg = blockIdx.x;
    int b = bg >> 5, g = bg & 31;
    const float4* xp = (const float4*)(x + ((size_t)b * CH + g * 8) * SP);
    int tid = threadIdx.x;
    float s = 0.f, ss = 0.f;
    for (int i = tid; i < 8192; i += 256) {
        float4 u = xp[i];
        s  += (u.x + u.y) + (u.z + u.w);
        ss += (u.x * u.x + u.y * u.y) + (u.z * u.z + u.w * u.w);
    }
#pragma unroll
    for (int off = 32; off > 0; off >>= 1) {
        s  += __shfl_down(s, off);
        ss += __shfl_down(ss, off);
    }
    __shared__ float ws_s[4], ws_q[4], stat[2];
    int w = tid >> 6;
    if ((tid & 63) == 0) { ws_s[w] = s; ws_q[w] = ss; }
    __syncthreads();
    if (tid == 0) {
        float st = ws_s[0] + ws_s[1] + ws_s[2] + ws_s[3];
        float qt = ws_q[0] + ws_q[1] + ws_q[2] + ws_q[3];
        float mu = st * (1.f / 32768.f);
        float var = qt * (1.f / 32768.f) - mu * mu;
        float rs = rsqrtf(var + 1e-5f);
        stat[0] = mu; stat[1] = rs;
    }
    __syncthreads();
    if (tid < 8) {
        int c = g * 8 + tid;
        float mu = stat[0], rs = stat[1];
        float ga = gamma[c];
        a_out[b * CH + c] = rs * ga;
        b_out[b * CH + c] = beta[c] - mu * rs * ga;
    }
}

// ---------------------------------------------------------------------------
// Kernel 2: weight convert to bf16. wq gets the 1/8 attention scale folded in.
// wp is column-permuted to chan = n*64+d (matching O layout for proj GEMM).
// ---------------------------------------------------------------------------
__global__ __launch_bounds__(256) void wconv_kernel(
    const float* __restrict__ wq, const float* __restrict__ wk,
    const float* __restrict__ wv, const float* __restrict__ wp,
    u16* __restrict__ wqb, u16* __restrict__ wkb,
    u16* __restrict__ wvb, u16* __restrict__ wpb)
{
    int idx = blockIdx.x * 256 + threadIdx.x;   // 0..262143
    int m = idx >> 16, i = idx & 65535;
    if (m == 0)      wqb[i] = b16(wq[i] * SCALE_Q);
    else if (m == 1) wkb[i] = b16(wk[i]);
    else if (m == 2) wvb[i] = b16(wv[i]);
    else {
        int c = i >> 8, chan = i & 255;
        int n = chan >> 6, d = chan & 63;
        wpb[i] = b16(wp[c * 256 + d * 4 + n]);
    }
}

// ---------------------------------------------------------------------------
// Kernel 3: xprep — apply GN affine, transpose x to bf16 Xt [b][s][c].
// ---------------------------------------------------------------------------
__global__ __launch_bounds__(256) void xprep_kernel(
    const float* __restrict__ x, const float* __restrict__ aff_a,
    const float* __restrict__ aff_b, u16* __restrict__ xt)
{
    int b = blockIdx.z, c0 = blockIdx.y * 64, s0 = blockIdx.x * 64;
    int tid = threadIdx.x;
    __shared__ u16 Lt[64][72];   // [s][c], pitch 72 keeps uint4 rows aligned
    int cl = tid >> 2, sg = tid & 3;
    const float* xr = x + ((size_t)b * CH + c0 + cl) * SP + s0 + sg * 16;
    float aa = aff_a[b * CH + c0 + cl], bb = aff_b[b * CH + c0 + cl];
#pragma unroll
    for (int i = 0; i < 4; i++) {
        float4 v = *(const float4*)&xr[4 * i];
        int s = sg * 16 + 4 * i;
        Lt[s + 0][cl] = b16(fmaf(aa, v.x, bb));
        Lt[s + 1][cl] = b16(fmaf(aa, v.y, bb));
        Lt[s + 2][cl] = b16(fmaf(aa, v.z, bb));
        Lt[s + 3][cl] = b16(fmaf(aa, v.w, bb));
    }
    __syncthreads();
    int s = tid >> 2, ch = (tid & 3) * 2;
    u16* dst = xt + ((size_t)b * SP + s0 + s) * CH + c0;
    *(uint4*)&dst[ch * 8]       = *(const uint4*)&Lt[s][ch * 8];
    *(uint4*)&dst[(ch + 1) * 8] = *(const uint4*)&Lt[s][(ch + 1) * 8];
}

// ---------------------------------------------------------------------------
// Kernel 4: Q/K/V projection — MFMA GEMM, A/B frags straight from global
// (L2-resident bf16 W and Xt). No LDS in the K-loop, no barriers.
// Outputs: Q,K bf16 [z][s][d] (LDS transpose epilogue), V bf16 [z][d][s].
// ---------------------------------------------------------------------------
__global__ __launch_bounds__(256) void qkv_gemm_kernel(
    const u16* __restrict__ xt, const u16* __restrict__ wqb,
    const u16* __restrict__ wkb, const u16* __restrict__ wvb,
    const float* __restrict__ bq, const float* __restrict__ bk,
    const float* __restrict__ bv,
    u16* __restrict__ qt, u16* __restrict__ kt, u16* __restrict__ vt)
{
    int zz = blockIdx.y;            // b*3 + p
    int b = zz / 3, p = zz % 3;
    const u16* W = (p == 0) ? wqb : (p == 1) ? wkb : wvb;
    const float* bias = (p == 0) ? bq : (p == 1) ? bk : bv;
    float bscale = (p == 0) ? SCALE_Q : 1.f;
    int s0 = blockIdx.x * 64;
    int tid = threadIdx.x, w = tid >> 6, lane = tid & 63;
    int t = lane >> 4, ln = lane & 15;

    __shared__ u16 Ts[4 * 64 * 72];   // transpose staging (36 KB)

    f32x4 acc[4][4];
#pragma unroll
    for (int og = 0; og < 4; og++)
#pragma unroll
        for (int sg = 0; sg < 4; sg++)
            acc[og][sg] = (f32x4){0.f, 0.f, 0.f, 0.f};

    const u16* xb = xt + ((size_t)b * SP + s0) * CH;

#pragma unroll
    for (int ks = 0; ks < 8; ks++) {
        bf16x8 af[4], bf[4];
#pragma unroll
        for (int og = 0; og < 4; og++)
            af[og] = *(const bf16x8*)&W[(size_t)(w * 64 + og * 16 + ln) * CH + ks * 32 + t * 8];
#pragma unroll
        for (int sg = 0; sg < 4; sg++)
            bf[sg] = *(const bf16x8*)&xb[(size_t)(sg * 16 + ln) * CH + ks * 32 + t * 8];
#pragma unroll
        for (int og = 0; og < 4; og++)
#pragma unroll
            for (int sg = 0; sg < 4; sg++)
                acc[og][sg] = __builtin_amdgcn_mfma_f32_16x16x32_bf16(
                    af[og], bf[sg], acc[og][sg], 0, 0, 0);
    }

    // o = w*64 + og*16 + 4t + r  ->  d = o>>2 = w*16+og*4+t, head n = o&3 = r
    if (p < 2) {
        u16* out = (p == 0) ? qt : kt;
#pragma unroll
        for (int og = 0; og < 4; og++)
#pragma unroll
            for (int sg = 0; sg < 4; sg++)
#pragma unroll
                for (int r = 0; r < 4; r++) {
                    int o = w * 64 + og * 16 + 4 * t + r;
                    int d = w * 16 + og * 4 + t;
                    int s = sg * 16 + ln;
                    Ts[(r * 64 + s) * 72 + d] = b16(acc[og][sg][r] + bias[o] * bscale);
                }
        __syncthreads();
#pragma unroll
        for (int it = 0; it < 8; it++) {
            int idx = it * 256 + tid;
            int n = idx >> 9, s = (idx >> 3) & 63, dq = idx & 7;
            *(uint4*)&out[((size_t)(b * 4 + n) * SP + s0 + s) * HD + dq * 8] =
                *(const uint4*)&Ts[(n * 64 + s) * 72 + dq * 8];
        }
    } else {
#pragma unroll
        for (int og = 0; og < 4; og++)
#pragma unroll
            for (int sg = 0; sg < 4; sg++)
#pragma unroll
                for (int r = 0; r < 4; r++) {
                    int o = w * 64 + og * 16 + 4 * t + r;
                    int d = w * 16 + og * 4 + t;
                    int s = sg * 16 + ln;
                    Ts[(r * 64 + d) * 72 + s] = b16(acc[og][sg][r] + bias[o]);
                }
        __syncthreads();
#pragma unroll
        for (int it = 0; it < 8; it++) {
            int idx = it * 256 + tid;
            int n = idx >> 9, d = (idx >> 3) & 63, sq = idx & 7;
            *(uint4*)&vt[((size_t)(b * 4 + n) * HD + d) * SP + s0 + sq * 8] =
                *(const uint4*)&Ts[(n * 64 + d) * 72 + sq * 8];
        }
    }
}

// ---------------------------------------------------------------------------
// Kernel 5: MFMA flash attention, no-max softmax, k-split=2.
// Grid (z=8, qt=32, split=2) = 512 blocks = 2/CU. Block = 4 waves x 32 q.
// Per key-tile(64): QK^T (16 mfma) -> exp (no reductions, per-lane l) ->
// P pack (1 v_perm per pair) -> LDS roundtrip (wave-private, no barrier) ->
// PV (16 mfma). Double-buffered K/V staging, one barrier per tile.
// ---------------------------------------------------------------------------
__global__ __launch_bounds__(256) void attn_kernel(
    const u16* __restrict__ qtb, const u16* __restrict__ ktb,
    const u16* __restrict__ vtb, u16* __restrict__ opart,
    float* __restrict__ lpart)
{
    int z = blockIdx.x;
    int sq0 = blockIdx.y * 128;
    int sp = blockIdx.z;
    int kbase = sp * 2048;
    const u16* qz = qtb + (size_t)z * SP * HD;   // [s][d]
    const u16* kz = ktb + (size_t)z * SP * HD;   // [s][d]
    const u16* vz = vtb + (size_t)z * HD * SP;   // [d][s]

    int tid = threadIdx.x, w = tid >> 6, lane = tid & 63;
    int t = lane >> 4, ln = lane & 15;

    __shared__ __align__(16) u16 Kb[2][4096];
    __shared__ __align__(16) u16 Vb[2][4096];
    __shared__ __align__(16) u32 Pb[4][1024];

    // Q B-frags (n=q=ln, k=d): direct b128 from global, 1/8 scale already in wq
    bf16x8 qf[2][2];
#pragma unroll
    for (int qg = 0; qg < 2; qg++)
#pragma unroll
        for (int ds = 0; ds < 2; ds++)
            qf[qg][ds] = *(const bf16x8*)&qz[
                (size_t)(sq0 + w * 32 + qg * 16 + ln) * HD + ds * 32 + t * 8];

    // preload tile 0 (wave w stages groups 2w, 2w+1; g = kg*2+ds)
    uint4 kr[2], vr[2];
#pragma unroll
    for (int gi = 0; gi < 2; gi++) {
        int g = 2 * w + gi;
        kr[gi] = *(const uint4*)&kz[(size_t)(kbase + (g >> 1) * 16 + ln) * HD + (g & 1) * 32 + t * 8];
        vr[gi] = *(const uint4*)&vz[(size_t)((g >> 1) * 16 + ln) * SP + kbase + (g & 1) * 32 + t * 8];
    }
#pragma unroll
    for (int gi = 0; gi < 2; gi++) {
        int g = 2 * w + gi;
        *(uint4*)&Kb[0][g * 512 + lane * 8] = kr[gi];
        *(uint4*)&Vb[0][g * 512 + lane * 8] = vr[gi];
    }

    float lsum[2] = {0.f, 0.f};
    f32x4 oacc[2][4];
#pragma unroll
    for (int qg = 0; qg < 2; qg++)
#pragma unroll
        for (int dg = 0; dg < 4; dg++)
            oacc[qg][dg] = (f32x4){0.f, 0.f, 0.f, 0.f};

    for (int kti = 0; kti < 32; kti++) {
        int cb = kti & 1;
        __syncthreads();

        if (kti < 31) {
            int kt = kbase + (kti + 1) * 64;
#pragma unroll
            for (int gi = 0; gi < 2; gi++) {
                int g = 2 * w + gi;
                kr[gi] = *(const uint4*)&kz[(size_t)(kt + (g >> 1) * 16 + ln) * HD + (g & 1) * 32 + t * 8];
                vr[gi] = *(const uint4*)&vz[(size_t)((g >> 1) * 16 + ln) * SP + kt + (g & 1) * 32 + t * 8];
            }
        }

        // QK^T: sa[qg][kg], rows = key (kg*16+4t+r), cols = q (ln)
        f32x4 sa[2][4];
#pragma unroll
        for (int qg = 0; qg < 2; qg++)
#pragma unroll
            for (int kg = 0; kg < 4; kg++)
                sa[qg][kg] = (f32x4){0.f, 0.f, 0.f, 0.f};
#pragma unroll
        for (int ds = 0; ds < 2; ds++)
#pragma unroll
            for (int kg = 0; kg < 4; kg++) {
                bf16x8 kf = *(const bf16x8*)&Kb[cb][(kg * 2 + ds) * 512 + lane * 8];
#pragma unroll
                for (int qg = 0; qg < 2; qg++)
                    sa[qg][kg] = __builtin_amdgcn_mfma_f32_16x16x32_bf16(
                        kf, qf[qg][ds], sa[qg][kg], 0, 0, 0);
            }

        // exp (no max needed: |score| <~ 8), per-lane l partial, pack, P store
#pragma unroll
        for (int qg = 0; qg < 2; qg++) {
#pragma unroll
            for (int kg = 0; kg < 4; kg++) {
                float e0 = __expf(sa[qg][kg][0]);
                float e1 = __expf(sa[qg][kg][1]);
                float e2 = __expf(sa[qg][kg][2]);
                float e3 = __expf(sa[qg][kg][3]);
                lsum[qg] += (e0 + e1) + (e2 + e3);
                // truncating bf16 pack: one v_perm per pair
                u32 p0 = __builtin_amdgcn_perm(__float_as_uint(e1), __float_as_uint(e0), 0x07060302u);
                u32 p1 = __builtin_amdgcn_perm(__float_as_uint(e3), __float_as_uint(e2), 0x07060302u);
                int Lt = ln + 16 * (2 * (kg & 1) + (t >> 1));
                int ksg = kg >> 1;
                *(uint2*)&Pb[w][((qg * 2 + ksg) * 64 + Lt) * 4 + 2 * (t & 1)] =
                    make_uint2(p0, p1);
            }
        }

        // P A-frags (wave-private; in-wave DS ordering, no barrier)
        bf16x8 pf[2][2];
#pragma unroll
        for (int qg = 0; qg < 2; qg++)
#pragma unroll
            for (int ksg = 0; ksg < 2; ksg++)
                pf[qg][ksg] = *(const bf16x8*)&Pb[w][((qg * 2 + ksg) * 64 + lane) * 4];

        // PV: O[q][d] += P·V
#pragma unroll
        for (int ksg = 0; ksg < 2; ksg++)
#pragma unroll
            for (int dg = 0; dg < 4; dg++) {
                bf16x8 vf = *(const bf16x8*)&Vb[cb][(dg * 2 + ksg) * 512 + lane * 8];
#pragma unroll
                for (int qg = 0; qg < 2; qg++)
                    oacc[qg][dg] = __builtin_amdgcn_mfma_f32_16x16x32_bf16(
                        pf[qg][ksg], vf, oacc[qg][dg], 0, 0, 0);
            }

        if (kti < 31) {
            int nb = 1 - cb;
#pragma unroll
            for (int gi = 0; gi < 2; gi++) {
                int g = 2 * w + gi;
                *(uint4*)&Kb[nb][g * 512 + lane * 8] = kr[gi];
                *(uint4*)&Vb[nb][g * 512 + lane * 8] = vr[gi];
            }
        }
    }

    // l reduction (only once, at the end)
#pragma unroll
    for (int qg = 0; qg < 2; qg++) {
        lsum[qg] += __shfl_xor(lsum[qg], 16);
        lsum[qg] += __shfl_xor(lsum[qg], 32);
    }

    size_t obase = (size_t)(sp * 8 + z) * SP;
#pragma unroll
    for (int qg = 0; qg < 2; qg++)
#pragma unroll
        for (int dg = 0; dg < 4; dg++)
#pragma unroll
            for (int r = 0; r < 4; r++) {
                int q = sq0 + w * 32 + qg * 16 + 4 * t + r;
                opart[(obase + q) * HD + dg * 16 + ln] = b16(oacc[qg][dg][r]);
            }
    if (lane < 16) {
#pragma unroll
        for (int qg = 0; qg < 2; qg++)
            lpart[obase + sq0 + w * 32 + qg * 16 + ln] = lsum[qg];
    }
}

// ---------------------------------------------------------------------------
// Kernel 6: combine k-split halves: Ot[b][s][n*64+d] = (O0+O1)/(l0+l1), bf16.
// ---------------------------------------------------------------------------
__global__ __launch_bounds__(256) void combine_kernel(
    const u16* __restrict__ opart, const float* __restrict__ lpart,
    u16* __restrict__ ot)
{
    int z = blockIdx.x;
    int q0 = blockIdx.y * 32;
    int tid = threadIdx.x;
    int q = q0 + (tid >> 3), dq = tid & 7;
    int b = z >> 2, n = z & 3;
    size_t i0 = ((size_t)z * SP + q) * HD + dq * 8;
    size_t i1 = ((size_t)(8 + z) * SP + q) * HD + dq * 8;
    uint4 a = *(const uint4*)&opart[i0];
    uint4 c = *(const uint4*)&opart[i1];
    float l = lpart[(size_t)z * SP + q] + lpart[(size_t)(8 + z) * SP + q];
    float inv = 1.f / l;
    u32 av[4] = {a.x, a.y, a.z, a.w}, cv[4] = {c.x, c.y, c.z, c.w};
    u32 res[4];
#pragma unroll
    for (int i = 0; i < 4; i++) {
        float lo = __uint_as_float(av[i] << 16) + __uint_as_float(cv[i] << 16);
        float hi = __uint_as_float(av[i] & 0xffff0000u) + __uint_as_float(cv[i] & 0xffff0000u);
        u16 rl = b16(lo * inv), rh = b16(hi * inv);
        res[i] = ((u32)rh << 16) | rl;
    }
    uint4 o4 = make_uint4(res[0], res[1], res[2], res[3]);
    *(uint4*)&ot[((size_t)b * SP + q) * CH + n * 64 + dq * 8] = o4;
}

// ---------------------------------------------------------------------------
// Kernel 7: output projection + residual — MFMA GEMM, frags from global.
// out[b][c][s] = x + bp[c] + sum_chan Wpb[c][chan] * Ot[b][s][chan]
// ---------------------------------------------------------------------------
__global__ __launch_bounds__(256) void proj_gemm_kernel(
    const u16* __restrict__ ot, const u16* __restrict__ wpb,
    const float* __restrict__ bp, const float* __restrict__ x,
    float* __restrict__ out)
{
    int b = blockIdx.y;
    int s0 = blockIdx.x * 64;
    int tid = threadIdx.x, w = tid >> 6, lane = tid & 63;
    int t = lane >> 4, ln = lane & 15;

    f32x4 acc[4][4];
#pragma unroll
    for (int og = 0; og < 4; og++)
#pragma unroll
        for (int sg = 0; sg < 4; sg++)
            acc[og][sg] = (f32x4){0.f, 0.f, 0.f, 0.f};

    const u16* ob = ot + ((size_t)b * SP + s0) * CH;

#pragma unroll
    for (int ks = 0; ks < 8; ks++) {
        bf16x8 af[4], bf[4];
#pragma unroll
        for (int og = 0; og < 4; og++)
            af[og] = *(const bf16x8*)&wpb[(size_t)(w * 64 + og * 16 + ln) * CH + ks * 32 + t * 8];
#pragma unroll
        for (int sg = 0; sg < 4; sg++)
            bf[sg] = *(const bf16x8*)&ob[(size_t)(sg * 16 + ln) * CH + ks * 32 + t * 8];
#pragma unroll
        for (int og = 0; og < 4; og++)
#pragma unroll
            for (int sg = 0; sg < 4; sg++)
                acc[og][sg] = __builtin_amdgcn_mfma_f32_16x16x32_bf16(
                    af[og], bf[sg], acc[og][sg], 0, 0, 0);
    }

#pragma unroll
    for (int og = 0; og < 4; og++)
#pragma unroll
        for (int sg = 0; sg < 4; sg++)
#pragma unroll
            for (int r = 0; r < 4; r++) {
                int c = w * 64 + og * 16 + 4 * t + r;
                size_t idx = ((size_t)b * CH + c) * SP + s0 + sg * 16 + ln;
                out[idx] = acc[og][sg][r] + bp[c] + x[idx];
            }
}

// ---------------------------------------------------------------------------
extern "C" void kernel_launch(void* const* d_in, const int* in_sizes, int n_in,
                              void* d_out, int out_size, void* d_ws, size_t ws_size,
                              hipStream_t stream)
{
    const float* x     = (const float*)d_in[0];
    const float* gamma = (const float*)d_in[1];
    const float* beta  = (const float*)d_in[2];
    const float* wq = (const float*)d_in[3]; const float* bq = (const float*)d_in[4];
    const float* wk = (const float*)d_in[5]; const float* bk = (const float*)d_in[6];
    const float* wv = (const float*)d_in[7]; const float* bv = (const float*)d_in[8];
    const float* wp = (const float*)d_in[9]; const float* bp = (const float*)d_in[10];
    float* out = (float*)d_out;

    // ws layout (~24.8 MB): aff | Wb x4 | Qt | Kt | Vt | Xt(->Ot) | Opart | lpart
    const size_t TEN = (size_t)8 * SP * HD;   // 2,097,152 elements
    char* wsb = (char*)d_ws;
    float* aff_a = (float*)wsb;
    float* aff_b = aff_a + 512;
    u16* wqb = (u16*)(wsb + 4096);
    u16* wkb = wqb + 65536;
    u16* wvb = wkb + 65536;
    u16* wpb = wvb + 65536;
    u16* qt  = wpb + 65536;
    u16* kt  = qt + TEN;
    u16* vt  = kt + TEN;
    u16* xt  = vt + TEN;                     // 2*4096*256 = TEN elements
    u16* ot  = xt;                           // Xt dead after qkv; reuse for Ot
    u16* opart = xt + TEN;                   // 2 splits x TEN
    float* lpart = (float*)(opart + 2 * TEN);  // 2 x 8 x 4096 floats

    gn_stats_kernel<<<dim3(64), dim3(256), 0, stream>>>(x, gamma, beta, aff_a, aff_b);
    wconv_kernel<<<dim3(1024), dim3(256), 0, stream>>>(wq, wk, wv, wp, wqb, wkb, wvb, wpb);
    xprep_kernel<<<dim3(64, 4, 2), dim3(256), 0, stream>>>(x, aff_a, aff_b, xt);
    qkv_gemm_kernel<<<dim3(64, 6), dim3(256), 0, stream>>>(
        xt, wqb, wkb, wvb, bq, bk, bv, qt, kt, vt);
    attn_kernel<<<dim3(8, 32, 2), dim3(256), 0, stream>>>(qt, kt, vt, opart, lpart);
    combine_kernel<<<dim3(8, 128), dim3(256), 0, stream>>>(opart, lpart, ot);
    proj_gemm_kernel<<<dim3(64, 2), dim3(256), 0, stream>>>(ot, wpb, bp, x, out);
}

// Round 4
// 199.173 us; speedup vs baseline: 5.2990x; 1.0651x over previous
//
#include <hip/hip_runtime.h>

#define CH 256
#define NHEAD 4
#define HD 64
#define SP 4096
#define NB 2
// softmax scale 1/8 with log2(e) folded in (we use exp2)
#define QSCALE 0.1803368801111204f

typedef __attribute__((ext_vector_type(8))) short bf16x8;   // MFMA A/B frag
typedef __attribute__((ext_vector_type(4))) float f32x4;    // MFMA C/D frag
typedef unsigned int u32;
typedef unsigned short u16;

__device__ inline u16 b16(float f) {
    u32 u = __float_as_uint(f);
    return (u16)((u + 0x8000u) >> 16);
}
__device__ inline float fexp2(float x) { return __builtin_amdgcn_exp2f(x); }

// ---------------------------------------------------------------------------
// Kernel 1a: GroupNorm partial sums. 256 blocks: (b,g) x 4 spatial quarters.
// ---------------------------------------------------------------------------
__global__ __launch_bounds__(256) void gn_partial_kernel(
    const float* __restrict__ x, float2* __restrict__ part)
{
    int bgq = blockIdx.x;            // (b*32+g)*4 + qtr
    int bg = bgq >> 2, qtr = bgq & 3;
    const float4* xp = (const float4*)(x + (size_t)bg * 8 * SP) + qtr * 2048;
    int tid = threadIdx.x;
    float s = 0.f, ss = 0.f;
    for (int i = tid; i < 2048; i += 256) {
        float4 u = xp[i];
        s  += (u.x + u.y) + (u.z + u.w);
        ss += (u.x * u.x + u.y * u.y) + (u.z * u.z + u.w * u.w);
    }
#pragma unroll
    for (int off = 32; off > 0; off >>= 1) {
        s  += __shfl_down(s, off);
        ss += __shfl_down(ss, off);
    }
    __shared__ float ws_s[4], ws_q[4];
    int w = tid >> 6;
    if ((tid & 63) == 0) { ws_s[w] = s; ws_q[w] = ss; }
    __syncthreads();
    if (tid == 0)
        part[bgq] = make_float2(ws_s[0] + ws_s[1] + ws_s[2] + ws_s[3],
                                ws_q[0] + ws_q[1] + ws_q[2] + ws_q[3]);
}

// ---------------------------------------------------------------------------
// Kernel 1b: finalize GN affine a[c], b[c] (hn = a*x + b).
// ---------------------------------------------------------------------------
__global__ __launch_bounds__(64) void gn_final_kernel(
    const float2* __restrict__ part, const float* __restrict__ gamma,
    const float* __restrict__ beta, float* __restrict__ a_out,
    float* __restrict__ b_out)
{
    int bg = threadIdx.x;            // 0..63
    float s = 0.f, ss = 0.f;
#pragma unroll
    for (int q = 0; q < 4; q++) { float2 p = part[bg * 4 + q]; s += p.x; ss += p.y; }
    float mu = s * (1.f / 32768.f);
    float var = ss * (1.f / 32768.f) - mu * mu;
    float rs = rsqrtf(var + 1e-5f);
    int b = bg >> 5, g = bg & 31;
#pragma unroll
    for (int j = 0; j < 8; j++) {
        int c = g * 8 + j;
        float ga = gamma[c];
        a_out[b * CH + c] = rs * ga;
        b_out[b * CH + c] = beta[c] - mu * rs * ga;
    }
}

// ---------------------------------------------------------------------------
// Kernel 2: weight convert to bf16. wq gets QSCALE (1/8 * log2e) folded in.
// wp column-permuted to chan = n*64+d (matches O layout for proj GEMM).
// ---------------------------------------------------------------------------
__global__ __launch_bounds__(256) void wconv_kernel(
    const float* __restrict__ wq, const float* __restrict__ wk,
    const float* __restrict__ wv, const float* __restrict__ wp,
    u16* __restrict__ wqb, u16* __restrict__ wkb,
    u16* __restrict__ wvb, u16* __restrict__ wpb)
{
    int idx = blockIdx.x * 256 + threadIdx.x;   // 0..262143
    int m = idx >> 16, i = idx & 65535;
    if (m == 0)      wqb[i] = b16(wq[i] * QSCALE);
    else if (m == 1) wkb[i] = b16(wk[i]);
    else if (m == 2) wvb[i] = b16(wv[i]);
    else {
        int c = i >> 8, chan = i & 255;
        int n = chan >> 6, d = chan & 63;
        wpb[i] = b16(wp[c * 256 + d * 4 + n]);
    }
}

// ---------------------------------------------------------------------------
// Kernel 3: xprep — apply GN affine, transpose x to bf16 Xt [b][s][c].
// ---------------------------------------------------------------------------
__global__ __launch_bounds__(256) void xprep_kernel(
    const float* __restrict__ x, const float* __restrict__ aff_a,
    const float* __restrict__ aff_b, u16* __restrict__ xt)
{
    int b = blockIdx.z, c0 = blockIdx.y * 64, s0 = blockIdx.x * 64;
    int tid = threadIdx.x;
    __shared__ u16 Lt[64][72];
    int cl = tid >> 2, sg = tid & 3;
    const float* xr = x + ((size_t)b * CH + c0 + cl) * SP + s0 + sg * 16;
    float aa = aff_a[b * CH + c0 + cl], bb = aff_b[b * CH + c0 + cl];
#pragma unroll
    for (int i = 0; i < 4; i++) {
        float4 v = *(const float4*)&xr[4 * i];
        int s = sg * 16 + 4 * i;
        Lt[s + 0][cl] = b16(fmaf(aa, v.x, bb));
        Lt[s + 1][cl] = b16(fmaf(aa, v.y, bb));
        Lt[s + 2][cl] = b16(fmaf(aa, v.z, bb));
        Lt[s + 3][cl] = b16(fmaf(aa, v.w, bb));
    }
    __syncthreads();
    int s = tid >> 2, ch = (tid & 3) * 2;
    u16* dst = xt + ((size_t)b * SP + s0 + s) * CH + c0;
    *(uint4*)&dst[ch * 8]       = *(const uint4*)&Lt[s][ch * 8];
    *(uint4*)&dst[(ch + 1) * 8] = *(const uint4*)&Lt[s][(ch + 1) * 8];
}

// ---------------------------------------------------------------------------
// Kernel 4: Q/K/V projection — MFMA GEMM, frags straight from global.
// s-tile 32 -> grid (128, 6) = 768 blocks (3/CU).
// Outputs: Q bf16 [z][s][d];  K,V bf16 PACKED in MFMA-frag order:
//   ktp[z][tile64][g=kg*2+ds][lane][8]  (A-frag for QK^T)
//   vtp[z][tile64][g=dg*2+ks][lane][8]  (B-frag for PV)
// ---------------------------------------------------------------------------
__global__ __launch_bounds__(256) void qkv_gemm_kernel(
    const u16* __restrict__ xt, const u16* __restrict__ wqb,
    const u16* __restrict__ wkb, const u16* __restrict__ wvb,
    const float* __restrict__ bq, const float* __restrict__ bk,
    const float* __restrict__ bv,
    u16* __restrict__ qt, u16* __restrict__ ktp, u16* __restrict__ vtp)
{
    int zz = blockIdx.y;            // b*3 + p
    int b = zz / 3, p = zz % 3;
    const u16* W = (p == 0) ? wqb : (p == 1) ? wkb : wvb;
    const float* bias = (p == 0) ? bq : (p == 1) ? bk : bv;
    float bs = (p == 0) ? QSCALE : 1.f;
    int s0 = blockIdx.x * 32;
    int tid = threadIdx.x, w = tid >> 6, lane = tid & 63;
    int t = lane >> 4, ln = lane & 15;

    __shared__ u16 Ts[10240];   // Q/K: [n][s32][72]; V: [n][d64][40]

    f32x4 acc[4][2];
#pragma unroll
    for (int og = 0; og < 4; og++)
#pragma unroll
        for (int sg = 0; sg < 2; sg++)
            acc[og][sg] = (f32x4){0.f, 0.f, 0.f, 0.f};

    const u16* xb = xt + ((size_t)b * SP + s0) * CH;

#pragma unroll
    for (int ks = 0; ks < 8; ks++) {
        bf16x8 af[4], bf[2];
#pragma unroll
        for (int og = 0; og < 4; og++)
            af[og] = *(const bf16x8*)&W[(size_t)(w * 64 + og * 16 + ln) * CH + ks * 32 + t * 8];
#pragma unroll
        for (int sg = 0; sg < 2; sg++)
            bf[sg] = *(const bf16x8*)&xb[(size_t)(sg * 16 + ln) * CH + ks * 32 + t * 8];
#pragma unroll
        for (int og = 0; og < 4; og++)
#pragma unroll
            for (int sg = 0; sg < 2; sg++)
                acc[og][sg] = __builtin_amdgcn_mfma_f32_16x16x32_bf16(
                    af[og], bf[sg], acc[og][sg], 0, 0, 0);
    }

    // C: rows o = w*64+og*16+4t+r  (d = o>>2 = w*16+og*4+t, head n = o&3 = r),
    //    cols s = sg*16+ln
    if (p < 2) {
        // stage [n][s][d] then emit
#pragma unroll
        for (int og = 0; og < 4; og++)
#pragma unroll
            for (int sg = 0; sg < 2; sg++)
#pragma unroll
                for (int r = 0; r < 4; r++) {
                    int o = w * 64 + og * 16 + 4 * t + r;
                    Ts[(r * 32 + sg * 16 + ln) * 72 + (w * 16 + og * 4 + t)] =
                        b16(acc[og][sg][r] + bias[o] * bs);
                }
        __syncthreads();
        if (p == 0) {
            // Q [z][s][d]
#pragma unroll
            for (int it = 0; it < 4; it++) {
                int idx = it * 256 + tid;
                int o8 = idx & 7, sl = (idx >> 3) & 31, n = idx >> 8;
                *(uint4*)&qt[((size_t)(b * 4 + n) * SP + s0 + sl) * HD + o8 * 8] =
                    *(const uint4*)&Ts[(n * 32 + sl) * 72 + o8 * 8];
            }
        } else {
            // K packed frag order
#pragma unroll
            for (int it = 0; it < 4; it++) {
                int idx = it * 256 + tid;
                int o8 = idx & 7, sl = (idx >> 3) & 31, n = idx >> 8;
                int key = s0 + sl;
                int g = ((key >> 4) & 3) * 2 + (o8 >> 2);
                int lp = (key & 15) + 16 * (o8 & 3);
                *(uint4*)&ktp[(size_t)(b * 4 + n) * SP * HD +
                              (size_t)(key >> 6) * 4096 + g * 512 + lp * 8] =
                    *(const uint4*)&Ts[(n * 32 + sl) * 72 + o8 * 8];
            }
        }
    } else {
        // V: stage [n][d][s] then emit packed frag order
#pragma unroll
        for (int og = 0; og < 4; og++)
#pragma unroll
            for (int sg = 0; sg < 2; sg++)
#pragma unroll
                for (int r = 0; r < 4; r++) {
                    int o = w * 64 + og * 16 + 4 * t + r;
                    Ts[(r * 64 + w * 16 + og * 4 + t) * 40 + sg * 16 + ln] =
                        b16(acc[og][sg][r] + bias[o]);
                }
        __syncthreads();
#pragma unroll
        for (int it = 0; it < 4; it++) {
            int idx = it * 256 + tid;
            int so8 = idx & 3, d = (idx >> 2) & 63, n = idx >> 8;
            int key = s0 + so8 * 8;
            int g = ((d >> 4) & 3) * 2 + ((key >> 5) & 1);
            int lp = (d & 15) + 16 * ((key >> 3) & 3);
            *(uint4*)&vtp[(size_t)(b * 4 + n) * SP * HD +
                          (size_t)(key >> 6) * 4096 + g * 512 + lp * 8] =
                *(const uint4*)&Ts[(n * 64 + d) * 40 + so8 * 8];
        }
    }
}

// ---------------------------------------------------------------------------
// Kernel 5: MFMA flash attention. q=256/block (64/wave, qg=4), k-split=4.
// Grid 512 (2/CU). z = blockIdx.x & 7 -> XCD-local K/V. No-max softmax via
// exp2 (scale folded in wq). K/V staged from packed global (b128 copy) with
// double buffer; P round-trip uses two alternating wave-private regions,
// exp/pack of qg+1 overlaps P-read latency of qg.
// ---------------------------------------------------------------------------
__global__ __launch_bounds__(256) void attn_kernel(
    const u16* __restrict__ qtb, const u16* __restrict__ ktp,
    const u16* __restrict__ vtp, u16* __restrict__ opart,
    float* __restrict__ lpart)
{
    int bx = blockIdx.x;
    int z = bx & 7, qt_i = (bx >> 3) & 15, sp = bx >> 7;
    int sq0 = qt_i * 256;
    int tile0 = sp * 16;
    const u16* qz = qtb + (size_t)z * SP * HD;
    const u16* kz = ktp + (size_t)z * SP * HD;
    const u16* vz = vtp + (size_t)z * SP * HD;

    int tid = threadIdx.x, w = tid >> 6, l = tid & 63;
    int t = l >> 4, ln = l & 15;

    __shared__ __align__(16) u16 Kb[2][4096];
    __shared__ __align__(16) u16 Vb[2][4096];
    __shared__ __align__(16) u32 Pb[4][2][512];

    // Q B-frags [qg][ds], direct b128 (scale already folded into wq/bq)
    bf16x8 qf[4][2];
#pragma unroll
    for (int qg = 0; qg < 4; qg++)
#pragma unroll
        for (int ds = 0; ds < 2; ds++)
            qf[qg][ds] = *(const bf16x8*)&qz[
                (size_t)(sq0 + w * 64 + qg * 16 + ln) * HD + ds * 32 + t * 8];

    // preload tile 0: wave w copies groups 2w, 2w+1 (packed: b128 straight copy)
    uint4 kr[2], vr[2];
#pragma unroll
    for (int gi = 0; gi < 2; gi++) {
        int g = 2 * w + gi;
        kr[gi] = *(const uint4*)&kz[(size_t)tile0 * 4096 + g * 512 + l * 8];
        vr[gi] = *(const uint4*)&vz[(size_t)tile0 * 4096 + g * 512 + l * 8];
    }
#pragma unroll
    for (int gi = 0; gi < 2; gi++) {
        int g = 2 * w + gi;
        *(uint4*)&Kb[0][g * 512 + l * 8] = kr[gi];
        *(uint4*)&Vb[0][g * 512 + l * 8] = vr[gi];
    }

    float lsum[4] = {0.f, 0.f, 0.f, 0.f};
    f32x4 oacc[4][4];
#pragma unroll
    for (int qg = 0; qg < 4; qg++)
#pragma unroll
        for (int dg = 0; dg < 4; dg++)
            oacc[qg][dg] = (f32x4){0.f, 0.f, 0.f, 0.f};

    f32x4 sa[4][4];

    auto ep = [&](int qg) {   // exp2 + pack + wave-private P store
#pragma unroll
        for (int kg = 0; kg < 4; kg++) {
            float e0 = fexp2(sa[qg][kg][0]);
            float e1 = fexp2(sa[qg][kg][1]);
            float e2 = fexp2(sa[qg][kg][2]);
            float e3 = fexp2(sa[qg][kg][3]);
            lsum[qg] += (e0 + e1) + (e2 + e3);
            u32 p0 = __builtin_amdgcn_perm(__float_as_uint(e1), __float_as_uint(e0), 0x07060302u);
            u32 p1 = __builtin_amdgcn_perm(__float_as_uint(e3), __float_as_uint(e2), 0x07060302u);
            int Lt = ln + 16 * (2 * (kg & 1) + (t >> 1));
            int ksg = kg >> 1;
            *(uint2*)&Pb[w][qg & 1][(ksg * 64 + Lt) * 4 + 2 * (t & 1)] =
                make_uint2(p0, p1);
        }
    };

    for (int kti = 0; kti < 16; kti++) {
        int cb = kti & 1;
        __syncthreads();

        if (kti < 15) {
            size_t nb = (size_t)(tile0 + kti + 1) * 4096;
#pragma unroll
            for (int gi = 0; gi < 2; gi++) {
                int g = 2 * w + gi;
                kr[gi] = *(const uint4*)&kz[nb + g * 512 + l * 8];
                vr[gi] = *(const uint4*)&vz[nb + g * 512 + l * 8];
            }
        }

        // QK^T for all qg (kf shared in-flight)
#pragma unroll
        for (int qg = 0; qg < 4; qg++)
#pragma unroll
            for (int kg = 0; kg < 4; kg++)
                sa[qg][kg] = (f32x4){0.f, 0.f, 0.f, 0.f};
#pragma unroll
        for (int ds = 0; ds < 2; ds++)
#pragma unroll
            for (int kg = 0; kg < 4; kg++) {
                bf16x8 kf = *(const bf16x8*)&Kb[cb][(kg * 2 + ds) * 512 + l * 8];
#pragma unroll
                for (int qg = 0; qg < 4; qg++)
                    sa[qg][kg] = __builtin_amdgcn_mfma_f32_16x16x32_bf16(
                        kf, qf[qg][ds], sa[qg][kg], 0, 0, 0);
            }

        // V frags (shared across qg)
        bf16x8 vf[2][4];
#pragma unroll
        for (int ksg = 0; ksg < 2; ksg++)
#pragma unroll
            for (int dg = 0; dg < 4; dg++)
                vf[ksg][dg] = *(const bf16x8*)&Vb[cb][(dg * 2 + ksg) * 512 + l * 8];

        // softmax + PV, software-pipelined over qg
        ep(0);
#pragma unroll
        for (int qg = 0; qg < 4; qg++) {
            if (qg < 3) ep(qg + 1);
            bf16x8 pf[2];
#pragma unroll
            for (int ksg = 0; ksg < 2; ksg++)
                pf[ksg] = *(const bf16x8*)&Pb[w][qg & 1][(ksg * 64 + l) * 4];
#pragma unroll
            for (int ksg = 0; ksg < 2; ksg++)
#pragma unroll
                for (int dg = 0; dg < 4; dg++)
                    oacc[qg][dg] = __builtin_amdgcn_mfma_f32_16x16x32_bf16(
                        pf[ksg], vf[ksg][dg], oacc[qg][dg], 0, 0, 0);
        }

        if (kti < 15) {
            int nb = 1 - cb;
#pragma unroll
            for (int gi = 0; gi < 2; gi++) {
                int g = 2 * w + gi;
                *(uint4*)&Kb[nb][g * 512 + l * 8] = kr[gi];
                *(uint4*)&Vb[nb][g * 512 + l * 8] = vr[gi];
            }
        }
    }

    // single l reduction at the end
#pragma unroll
    for (int qg = 0; qg < 4; qg++) {
        lsum[qg] += __shfl_xor(lsum[qg], 16);
        lsum[qg] += __shfl_xor(lsum[qg], 32);
    }

    size_t obase = (size_t)(sp * 8 + z) * SP;
#pragma unroll
    for (int qg = 0; qg < 4; qg++)
#pragma unroll
        for (int dg = 0; dg < 4; dg++)
#pragma unroll
            for (int r = 0; r < 4; r++) {
                int q = sq0 + w * 64 + qg * 16 + 4 * t + r;
                opart[(obase + q) * HD + dg * 16 + ln] = b16(oacc[qg][dg][r]);
            }
    if (t == 0)
#pragma unroll
        for (int qg = 0; qg < 4; qg++)
            lpart[obase + sq0 + w * 64 + qg * 16 + ln] = lsum[qg];
}

// ---------------------------------------------------------------------------
// Kernel 6: combine 4 k-split parts: Ot[b][s][n*64+d] = sum O_sp / sum l_sp.
// ---------------------------------------------------------------------------
__global__ __launch_bounds__(256) void combine_kernel(
    const u16* __restrict__ opart, const float* __restrict__ lpart,
    u16* __restrict__ ot)
{
    int z = blockIdx.x;
    int q0 = blockIdx.y * 32;
    int tid = threadIdx.x;
    int q = q0 + (tid >> 3), dq = tid & 7;
    int b = z >> 2, n = z & 3;
    float acc[8] = {0.f, 0.f, 0.f, 0.f, 0.f, 0.f, 0.f, 0.f};
    float lt = 0.f;
#pragma unroll
    for (int sp = 0; sp < 4; sp++) {
        size_t base = (size_t)(sp * 8 + z) * SP + q;
        uint4 a = *(const uint4*)&opart[base * HD + dq * 8];
        lt += lpart[base];
        u32 av[4] = {a.x, a.y, a.z, a.w};
#pragma unroll
        for (int i = 0; i < 4; i++) {
            acc[2 * i + 0] += __uint_as_float(av[i] << 16);
            acc[2 * i + 1] += __uint_as_float(av[i] & 0xffff0000u);
        }
    }
    float inv = 1.f / lt;
    u32 res[4];
#pragma unroll
    for (int i = 0; i < 4; i++) {
        u16 rl = b16(acc[2 * i + 0] * inv);
        u16 rh = b16(acc[2 * i + 1] * inv);
        res[i] = ((u32)rh << 16) | rl;
    }
    *(uint4*)&ot[((size_t)b * SP + q) * CH + n * 64 + dq * 8] =
        make_uint4(res[0], res[1], res[2], res[3]);
}

// ---------------------------------------------------------------------------
// Kernel 7: output projection + residual — MFMA GEMM, s-tile 32 (256 blocks).
// ---------------------------------------------------------------------------
__global__ __launch_bounds__(256) void proj_gemm_kernel(
    const u16* __restrict__ ot, const u16* __restrict__ wpb,
    const float* __restrict__ bp, const float* __restrict__ x,
    float* __restrict__ out)
{
    int b = blockIdx.y;
    int s0 = blockIdx.x * 32;
    int tid = threadIdx.x, w = tid >> 6, lane = tid & 63;
    int t = lane >> 4, ln = lane & 15;

    f32x4 acc[4][2];
#pragma unroll
    for (int og = 0; og < 4; og++)
#pragma unroll
        for (int sg = 0; sg < 2; sg++)
            acc[og][sg] = (f32x4){0.f, 0.f, 0.f, 0.f};

    const u16* ob = ot + ((size_t)b * SP + s0) * CH;

#pragma unroll
    for (int ks = 0; ks < 8; ks++) {
        bf16x8 af[4], bf[2];
#pragma unroll
        for (int og = 0; og < 4; og++)
            af[og] = *(const bf16x8*)&wpb[(size_t)(w * 64 + og * 16 + ln) * CH + ks * 32 + t * 8];
#pragma unroll
        for (int sg = 0; sg < 2; sg++)
            bf[sg] = *(const bf16x8*)&ob[(size_t)(sg * 16 + ln) * CH + ks * 32 + t * 8];
#pragma unroll
        for (int og = 0; og < 4; og++)
#pragma unroll
            for (int sg = 0; sg < 2; sg++)
                acc[og][sg] = __builtin_amdgcn_mfma_f32_16x16x32_bf16(
                    af[og], bf[sg], acc[og][sg], 0, 0, 0);
    }

#pragma unroll
    for (int og = 0; og < 4; og++)
#pragma unroll
        for (int sg = 0; sg < 2; sg++)
#pragma unroll
            for (int r = 0; r < 4; r++) {
                int c = w * 64 + og * 16 + 4 * t + r;
                size_t idx = ((size_t)b * CH + c) * SP + s0 + sg * 16 + ln;
                out[idx] = acc[og][sg][r] + bp[c] + x[idx];
            }
}

// ---------------------------------------------------------------------------
extern "C" void kernel_launch(void* const* d_in, const int* in_sizes, int n_in,
                              void* d_out, int out_size, void* d_ws, size_t ws_size,
                              hipStream_t stream)
{
    const float* x     = (const float*)d_in[0];
    const float* gamma = (const float*)d_in[1];
    const float* beta  = (const float*)d_in[2];
    const float* wq = (const float*)d_in[3]; const float* bq = (const float*)d_in[4];
    const float* wk = (const float*)d_in[5]; const float* bk = (const float*)d_in[6];
    const float* wv = (const float*)d_in[7]; const float* bv = (const float*)d_in[8];
    const float* wp = (const float*)d_in[9]; const float* bp = (const float*)d_in[10];
    float* out = (float*)d_out;

    const size_t TEN = (size_t)8 * SP * HD;   // 2,097,152 elements
    char* wsb = (char*)d_ws;
    float*  aff_a = (float*)wsb;              // 512 f
    float*  aff_b = aff_a + 512;              // 512 f
    float2* part  = (float2*)(wsb + 4096);    // 256 float2
    u16* wqb = (u16*)(wsb + 8192);
    u16* wkb = wqb + 65536;
    u16* wvb = wkb + 65536;
    u16* wpb = wvb + 65536;
    u16* qt  = wpb + 65536;
    u16* ktp = qt + TEN;
    u16* vtp = ktp + TEN;
    u16* xt  = vtp + TEN;                     // reused as Ot after qkv
    u16* ot  = xt;
    u16* opart = xt + TEN;                    // 4 splits x TEN
    float* lpart = (float*)(opart + 4 * TEN); // 4 x 8 x 4096 floats

    gn_partial_kernel<<<dim3(256), dim3(256), 0, stream>>>(x, part);
    gn_final_kernel<<<dim3(1), dim3(64), 0, stream>>>(part, gamma, beta, aff_a, aff_b);
    wconv_kernel<<<dim3(1024), dim3(256), 0, stream>>>(wq, wk, wv, wp, wqb, wkb, wvb, wpb);
    xprep_kernel<<<dim3(64, 4, 2), dim3(256), 0, stream>>>(x, aff_a, aff_b, xt);
    qkv_gemm_kernel<<<dim3(128, 6), dim3(256), 0, stream>>>(
        xt, wqb, wkb, wvb, bq, bk, bv, qt, ktp, vtp);
    attn_kernel<<<dim3(512), dim3(256), 0, stream>>>(qt, ktp, vtp, opart, lpart);
    combine_kernel<<<dim3(8, 128), dim3(256), 0, stream>>>(opart, lpart, ot);
    proj_gemm_kernel<<<dim3(128, 2), dim3(256), 0, stream>>>(ot, wpb, bp, x, out);
}

// Round 5
// 174.971 us; speedup vs baseline: 6.0320x; 1.1383x over previous
//
#include <hip/hip_runtime.h>

#define CH 256
#define NHEAD 4
#define HD 64
#define SP 4096
#define NB 2
// softmax scale 1/8 with log2(e) folded in (we use exp2)
#define QSCALE 0.1803368801111204f

typedef __attribute__((ext_vector_type(8))) short bf16x8;   // MFMA A/B frag
typedef __attribute__((ext_vector_type(4))) float f32x4;    // MFMA C/D frag
typedef unsigned int u32;
typedef unsigned short u16;

__device__ inline u16 b16(float f) {
    u32 u = __float_as_uint(f);
    return (u16)((u + 0x8000u) >> 16);
}
__device__ inline float fexp2(float x) { return __builtin_amdgcn_exp2f(x); }

// ---------------------------------------------------------------------------
// Kernel 1: fused GN partial sums (blocks 0..255) + weight convert (256..1279).
// wq gets QSCALE folded; wp column-permuted to chan = n*64+d.
// ---------------------------------------------------------------------------
__global__ __launch_bounds__(256) void prep_kernel(
    const float* __restrict__ x, float2* __restrict__ part,
    const float* __restrict__ wq, const float* __restrict__ wk,
    const float* __restrict__ wv, const float* __restrict__ wp,
    u16* __restrict__ wqb, u16* __restrict__ wkb,
    u16* __restrict__ wvb, u16* __restrict__ wpb)
{
    int tid = threadIdx.x;
    if (blockIdx.x < 256) {
        int bgq = blockIdx.x;            // (b*32+g)*4 + qtr
        int bg = bgq >> 2, qtr = bgq & 3;
        const float4* xp = (const float4*)(x + (size_t)bg * 8 * SP) + qtr * 2048;
        float s = 0.f, ss = 0.f;
        for (int i = tid; i < 2048; i += 256) {
            float4 u = xp[i];
            s  += (u.x + u.y) + (u.z + u.w);
            ss += (u.x * u.x + u.y * u.y) + (u.z * u.z + u.w * u.w);
        }
#pragma unroll
        for (int off = 32; off > 0; off >>= 1) {
            s  += __shfl_down(s, off);
            ss += __shfl_down(ss, off);
        }
        __shared__ float ws_s[4], ws_q[4];
        int w = tid >> 6;
        if ((tid & 63) == 0) { ws_s[w] = s; ws_q[w] = ss; }
        __syncthreads();
        if (tid == 0)
            part[bgq] = make_float2(ws_s[0] + ws_s[1] + ws_s[2] + ws_s[3],
                                    ws_q[0] + ws_q[1] + ws_q[2] + ws_q[3]);
    } else {
        int idx = (blockIdx.x - 256) * 256 + tid;   // 0..262143
        int m = idx >> 16, i = idx & 65535;
        if (m == 0)      wqb[i] = b16(wq[i] * QSCALE);
        else if (m == 1) wkb[i] = b16(wk[i]);
        else if (m == 2) wvb[i] = b16(wv[i]);
        else {
            int c = i >> 8, chan = i & 255;
            int n = chan >> 6, d = chan & 63;
            wpb[i] = b16(wp[c * 256 + d * 4 + n]);
        }
    }
}

// ---------------------------------------------------------------------------
// Kernel 2: xprep — finalize GN affine from partials (per-thread, redundant
// but L2-hot), apply, transpose x to bf16 Xt [b][s][c].
// ---------------------------------------------------------------------------
__global__ __launch_bounds__(256) void xprep_kernel(
    const float* __restrict__ x, const float2* __restrict__ part,
    const float* __restrict__ gamma, const float* __restrict__ beta,
    u16* __restrict__ xt)
{
    int b = blockIdx.z, c0 = blockIdx.y * 64, s0 = blockIdx.x * 64;
    int tid = threadIdx.x;
    __shared__ u16 Lt[64][72];
    int cl = tid >> 2, sg = tid & 3;
    int c = c0 + cl;
    int bg = b * 32 + (c >> 3);
    float s = 0.f, ss = 0.f;
#pragma unroll
    for (int q = 0; q < 4; q++) { float2 p = part[bg * 4 + q]; s += p.x; ss += p.y; }
    float mu = s * (1.f / 32768.f);
    float var = ss * (1.f / 32768.f) - mu * mu;
    float rs = rsqrtf(var + 1e-5f);
    float ga = gamma[c];
    float aa = rs * ga, bb = beta[c] - mu * rs * ga;

    const float* xr = x + ((size_t)b * CH + c) * SP + s0 + sg * 16;
#pragma unroll
    for (int i = 0; i < 4; i++) {
        float4 v = *(const float4*)&xr[4 * i];
        int sl = sg * 16 + 4 * i;
        Lt[sl + 0][cl] = b16(fmaf(aa, v.x, bb));
        Lt[sl + 1][cl] = b16(fmaf(aa, v.y, bb));
        Lt[sl + 2][cl] = b16(fmaf(aa, v.z, bb));
        Lt[sl + 3][cl] = b16(fmaf(aa, v.w, bb));
    }
    __syncthreads();
    int sl = tid >> 2, ch = (tid & 3) * 2;
    u16* dst = xt + ((size_t)b * SP + s0 + sl) * CH + c0;
    *(uint4*)&dst[ch * 8]       = *(const uint4*)&Lt[sl][ch * 8];
    *(uint4*)&dst[(ch + 1) * 8] = *(const uint4*)&Lt[sl][(ch + 1) * 8];
}

// ---------------------------------------------------------------------------
// Kernel 3: Q/K/V projection — MFMA GEMM, frags straight from global.
// Outputs: Q bf16 [z][s][d];  K,V bf16 packed in MFMA-frag order:
//   ktp[z][tile64][g=kg*2+ds][lane][8], vtp[z][tile64][g=dg*2+ks][lane][8]
// ---------------------------------------------------------------------------
__global__ __launch_bounds__(256) void qkv_gemm_kernel(
    const u16* __restrict__ xt, const u16* __restrict__ wqb,
    const u16* __restrict__ wkb, const u16* __restrict__ wvb,
    const float* __restrict__ bq, const float* __restrict__ bk,
    const float* __restrict__ bv,
    u16* __restrict__ qt, u16* __restrict__ ktp, u16* __restrict__ vtp)
{
    int zz = blockIdx.y;            // b*3 + p
    int b = zz / 3, p = zz % 3;
    const u16* W = (p == 0) ? wqb : (p == 1) ? wkb : wvb;
    const float* bias = (p == 0) ? bq : (p == 1) ? bk : bv;
    float bs = (p == 0) ? QSCALE : 1.f;
    int s0 = blockIdx.x * 32;
    int tid = threadIdx.x, w = tid >> 6, lane = tid & 63;
    int t = lane >> 4, ln = lane & 15;

    __shared__ u16 Ts[10240];   // Q/K: [n][s32][72]; V: [n][d64][40]

    f32x4 acc[4][2];
#pragma unroll
    for (int og = 0; og < 4; og++)
#pragma unroll
        for (int sg = 0; sg < 2; sg++)
            acc[og][sg] = (f32x4){0.f, 0.f, 0.f, 0.f};

    const u16* xb = xt + ((size_t)b * SP + s0) * CH;

#pragma unroll
    for (int ks = 0; ks < 8; ks++) {
        bf16x8 af[4], bf[2];
#pragma unroll
        for (int og = 0; og < 4; og++)
            af[og] = *(const bf16x8*)&W[(size_t)(w * 64 + og * 16 + ln) * CH + ks * 32 + t * 8];
#pragma unroll
        for (int sg = 0; sg < 2; sg++)
            bf[sg] = *(const bf16x8*)&xb[(size_t)(sg * 16 + ln) * CH + ks * 32 + t * 8];
#pragma unroll
        for (int og = 0; og < 4; og++)
#pragma unroll
            for (int sg = 0; sg < 2; sg++)
                acc[og][sg] = __builtin_amdgcn_mfma_f32_16x16x32_bf16(
                    af[og], bf[sg], acc[og][sg], 0, 0, 0);
    }

    // C rows o = w*64+og*16+4t+r (d = w*16+og*4+t, head n = r), cols s = sg*16+ln
    if (p < 2) {
#pragma unroll
        for (int og = 0; og < 4; og++)
#pragma unroll
            for (int sg = 0; sg < 2; sg++)
#pragma unroll
                for (int r = 0; r < 4; r++) {
                    int o = w * 64 + og * 16 + 4 * t + r;
                    Ts[(r * 32 + sg * 16 + ln) * 72 + (w * 16 + og * 4 + t)] =
                        b16(acc[og][sg][r] + bias[o] * bs);
                }
        __syncthreads();
        if (p == 0) {
#pragma unroll
            for (int it = 0; it < 4; it++) {
                int idx = it * 256 + tid;
                int o8 = idx & 7, sl = (idx >> 3) & 31, n = idx >> 8;
                *(uint4*)&qt[((size_t)(b * 4 + n) * SP + s0 + sl) * HD + o8 * 8] =
                    *(const uint4*)&Ts[(n * 32 + sl) * 72 + o8 * 8];
            }
        } else {
#pragma unroll
            for (int it = 0; it < 4; it++) {
                int idx = it * 256 + tid;
                int o8 = idx & 7, sl = (idx >> 3) & 31, n = idx >> 8;
                int key = s0 + sl;
                int g = ((key >> 4) & 3) * 2 + (o8 >> 2);
                int lp = (key & 15) + 16 * (o8 & 3);
                *(uint4*)&ktp[(size_t)(b * 4 + n) * SP * HD +
                              (size_t)(key >> 6) * 4096 + g * 512 + lp * 8] =
                    *(const uint4*)&Ts[(n * 32 + sl) * 72 + o8 * 8];
            }
        }
    } else {
#pragma unroll
        for (int og = 0; og < 4; og++)
#pragma unroll
            for (int sg = 0; sg < 2; sg++)
#pragma unroll
                for (int r = 0; r < 4; r++) {
                    int o = w * 64 + og * 16 + 4 * t + r;
                    Ts[(r * 64 + w * 16 + og * 4 + t) * 40 + sg * 16 + ln] =
                        b16(acc[og][sg][r] + bias[o]);
                }
        __syncthreads();
#pragma unroll
        for (int it = 0; it < 4; it++) {
            int idx = it * 256 + tid;
            int so8 = idx & 3, d = (idx >> 2) & 63, n = idx >> 8;
            int key = s0 + so8 * 8;
            int g = ((d >> 4) & 3) * 2 + ((key >> 5) & 1);
            int lp = (d & 15) + 16 * ((key >> 3) & 3);
            *(uint4*)&vtp[(size_t)(b * 4 + n) * SP * HD +
                          (size_t)(key >> 6) * 4096 + g * 512 + lp * 8] =
                *(const uint4*)&Ts[(n * 64 + d) * 40 + so8 * 8];
        }
    }
}

// ---------------------------------------------------------------------------
// Kernel 4: MFMA flash attention. q=128/block (32/wave, qg=2), k-split=4.
// Grid 1024 (4/CU). LDS 40 KB (Kb dbuf + Vb single + Pb) -> 4 blocks/CU;
// __launch_bounds__(256,4) caps VGPR <=128 -> 16 waves/CU.
// Vb single-buffered: V read only after exp, landed after 2nd barrier.
// sa zero-init folded into first MFMA (C = zero const).
// ---------------------------------------------------------------------------
__global__ __launch_bounds__(256, 4) void attn_kernel(
    const u16* __restrict__ qtb, const u16* __restrict__ ktp,
    const u16* __restrict__ vtp, u16* __restrict__ opart,
    float* __restrict__ lpart)
{
    int bx = blockIdx.x;
    int z = bx & 7, qt_i = (bx >> 3) & 31, sp = bx >> 8;
    int sq0 = qt_i * 128;
    int tile0 = sp * 16;
    const u16* qz = qtb + (size_t)z * SP * HD;
    const u16* kz = ktp + (size_t)z * SP * HD;
    const u16* vz = vtp + (size_t)z * SP * HD;

    int tid = threadIdx.x, w = tid >> 6, l = tid & 63;
    int t = l >> 4, ln = l & 15;

    __shared__ __align__(16) u16 Kb[2][4096];   // 16 KB (double)
    __shared__ __align__(16) u16 Vb[4096];      // 8 KB  (single)
    __shared__ __align__(16) u32 Pb[4][2][512]; // 16 KB (per-wave, per-qg)

    // Q B-frags [qg][ds] (scale folded into wq/bq)
    bf16x8 qf[2][2];
#pragma unroll
    for (int qg = 0; qg < 2; qg++)
#pragma unroll
        for (int ds = 0; ds < 2; ds++)
            qf[qg][ds] = *(const bf16x8*)&qz[
                (size_t)(sq0 + w * 32 + qg * 16 + ln) * HD + ds * 32 + t * 8];

    // preload tile 0 (wave w copies packed groups 2w, 2w+1)
    uint4 kr[2], vr[2];
#pragma unroll
    for (int gi = 0; gi < 2; gi++) {
        int g = 2 * w + gi;
        kr[gi] = *(const uint4*)&kz[(size_t)tile0 * 4096 + g * 512 + l * 8];
        vr[gi] = *(const uint4*)&vz[(size_t)tile0 * 4096 + g * 512 + l * 8];
    }
#pragma unroll
    for (int gi = 0; gi < 2; gi++) {
        int g = 2 * w + gi;
        *(uint4*)&Kb[0][g * 512 + l * 8] = kr[gi];
        *(uint4*)&Vb[g * 512 + l * 8] = vr[gi];
    }

    float lsum[2] = {0.f, 0.f};
    f32x4 oacc[2][4];
#pragma unroll
    for (int qg = 0; qg < 2; qg++)
#pragma unroll
        for (int dg = 0; dg < 4; dg++)
            oacc[qg][dg] = (f32x4){0.f, 0.f, 0.f, 0.f};

    const f32x4 z4 = {0.f, 0.f, 0.f, 0.f};
    f32x4 sa[2][4];

    auto ep = [&](int qg) {   // exp2 + pack + wave-private P store
#pragma unroll
        for (int kg = 0; kg < 4; kg++) {
            float e0 = fexp2(sa[qg][kg][0]);
            float e1 = fexp2(sa[qg][kg][1]);
            float e2 = fexp2(sa[qg][kg][2]);
            float e3 = fexp2(sa[qg][kg][3]);
            lsum[qg] += (e0 + e1) + (e2 + e3);
            u32 p0 = __builtin_amdgcn_perm(__float_as_uint(e1), __float_as_uint(e0), 0x07060302u);
            u32 p1 = __builtin_amdgcn_perm(__float_as_uint(e3), __float_as_uint(e2), 0x07060302u);
            int Lt = ln + 16 * (2 * (kg & 1) + (t >> 1));
            int ksg = kg >> 1;
            *(uint2*)&Pb[w][qg][(ksg * 64 + Lt) * 4 + 2 * (t & 1)] =
                make_uint2(p0, p1);
        }
    };

    for (int kti = 0; kti < 16; kti++) {
        int cb = kti & 1;
        __syncthreads();   // A: Kb[cb] and Vb hold tile kti

        if (kti < 15) {
            size_t nb = (size_t)(tile0 + kti + 1) * 4096;
#pragma unroll
            for (int gi = 0; gi < 2; gi++) {
                int g = 2 * w + gi;
                kr[gi] = *(const uint4*)&kz[nb + g * 512 + l * 8];
                vr[gi] = *(const uint4*)&vz[nb + g * 512 + l * 8];
            }
        }

        // QK^T (sa zero-init via z4 on first K-half)
#pragma unroll
        for (int kg = 0; kg < 4; kg++) {
            bf16x8 kf = *(const bf16x8*)&Kb[cb][(kg * 2 + 0) * 512 + l * 8];
#pragma unroll
            for (int qg = 0; qg < 2; qg++)
                sa[qg][kg] = __builtin_amdgcn_mfma_f32_16x16x32_bf16(
                    kf, qf[qg][0], z4, 0, 0, 0);
        }
#pragma unroll
        for (int kg = 0; kg < 4; kg++) {
            bf16x8 kf = *(const bf16x8*)&Kb[cb][(kg * 2 + 1) * 512 + l * 8];
#pragma unroll
            for (int qg = 0; qg < 2; qg++)
                sa[qg][kg] = __builtin_amdgcn_mfma_f32_16x16x32_bf16(
                    kf, qf[qg][1], sa[qg][kg], 0, 0, 0);
        }

        // land next K tile (Kb[1-cb] readers all finished before barrier A)
        if (kti < 15) {
#pragma unroll
            for (int gi = 0; gi < 2; gi++) {
                int g = 2 * w + gi;
                *(uint4*)&Kb[1 - cb][g * 512 + l * 8] = kr[gi];
            }
        }

        // softmax + PV, pipelined over qg (Pb wave-private, in-wave DS order)
        ep(0);
#pragma unroll
        for (int qg = 0; qg < 2; qg++) {
            if (qg == 0) ep(1);
            bf16x8 pf[2];
#pragma unroll
            for (int ksg = 0; ksg < 2; ksg++)
                pf[ksg] = *(const bf16x8*)&Pb[w][qg][(ksg * 64 + l) * 4];
#pragma unroll
            for (int ksg = 0; ksg < 2; ksg++)
#pragma unroll
                for (int dg = 0; dg < 4; dg++) {
                    bf16x8 vf = *(const bf16x8*)&Vb[(dg * 2 + ksg) * 512 + l * 8];
                    oacc[qg][dg] = __builtin_amdgcn_mfma_f32_16x16x32_bf16(
                        pf[ksg], vf, oacc[qg][dg], 0, 0, 0);
                }
        }

        __syncthreads();   // B: all waves done reading Vb
        if (kti < 15) {
#pragma unroll
            for (int gi = 0; gi < 2; gi++) {
                int g = 2 * w + gi;
                *(uint4*)&Vb[g * 512 + l * 8] = vr[gi];
            }
        }
    }

    // single l reduction at the end
#pragma unroll
    for (int qg = 0; qg < 2; qg++) {
        lsum[qg] += __shfl_xor(lsum[qg], 16);
        lsum[qg] += __shfl_xor(lsum[qg], 32);
    }

    size_t obase = (size_t)(sp * 8 + z) * SP;
#pragma unroll
    for (int qg = 0; qg < 2; qg++)
#pragma unroll
        for (int dg = 0; dg < 4; dg++)
#pragma unroll
            for (int r = 0; r < 4; r++) {
                int q = sq0 + w * 32 + qg * 16 + 4 * t + r;
                opart[(obase + q) * HD + dg * 16 + ln] = b16(oacc[qg][dg][r]);
            }
    if (t == 0)
#pragma unroll
        for (int qg = 0; qg < 2; qg++)
            lpart[obase + sq0 + w * 32 + qg * 16 + ln] = lsum[qg];
}

// ---------------------------------------------------------------------------
// Kernel 5: combine 4 k-split parts: Ot[b][s][n*64+d] = sum O_sp / sum l_sp.
// ---------------------------------------------------------------------------
__global__ __launch_bounds__(256) void combine_kernel(
    const u16* __restrict__ opart, const float* __restrict__ lpart,
    u16* __restrict__ ot)
{
    int z = blockIdx.x;
    int q0 = blockIdx.y * 32;
    int tid = threadIdx.x;
    int q = q0 + (tid >> 3), dq = tid & 7;
    int b = z >> 2, n = z & 3;
    float acc[8] = {0.f, 0.f, 0.f, 0.f, 0.f, 0.f, 0.f, 0.f};
    float lt = 0.f;
#pragma unroll
    for (int sp = 0; sp < 4; sp++) {
        size_t base = (size_t)(sp * 8 + z) * SP + q;
        uint4 a = *(const uint4*)&opart[base * HD + dq * 8];
        lt += lpart[base];
        u32 av[4] = {a.x, a.y, a.z, a.w};
#pragma unroll
        for (int i = 0; i < 4; i++) {
            acc[2 * i + 0] += __uint_as_float(av[i] << 16);
            acc[2 * i + 1] += __uint_as_float(av[i] & 0xffff0000u);
        }
    }
    float inv = 1.f / lt;
    u32 res[4];
#pragma unroll
    for (int i = 0; i < 4; i++) {
        u16 rl = b16(acc[2 * i + 0] * inv);
        u16 rh = b16(acc[2 * i + 1] * inv);
        res[i] = ((u32)rh << 16) | rl;
    }
    *(uint4*)&ot[((size_t)b * SP + q) * CH + n * 64 + dq * 8] =
        make_uint4(res[0], res[1], res[2], res[3]);
}

// ---------------------------------------------------------------------------
// Kernel 6: output projection + residual — MFMA GEMM, s-tile 16 (512 blocks).
// ---------------------------------------------------------------------------
__global__ __launch_bounds__(256) void proj_gemm_kernel(
    const u16* __restrict__ ot, const u16* __restrict__ wpb,
    const float* __restrict__ bp, const float* __restrict__ x,
    float* __restrict__ out)
{
    int b = blockIdx.y;
    int s0 = blockIdx.x * 16;
    int tid = threadIdx.x, w = tid >> 6, lane = tid & 63;
    int t = lane >> 4, ln = lane & 15;

    f32x4 acc[4];
#pragma unroll
    for (int og = 0; og < 4; og++)
        acc[og] = (f32x4){0.f, 0.f, 0.f, 0.f};

    const u16* ob = ot + ((size_t)b * SP + s0) * CH;

#pragma unroll
    for (int ks = 0; ks < 8; ks++) {
        bf16x8 af[4];
#pragma unroll
        for (int og = 0; og < 4; og++)
            af[og] = *(const bf16x8*)&wpb[(size_t)(w * 64 + og * 16 + ln) * CH + ks * 32 + t * 8];
        bf16x8 bf = *(const bf16x8*)&ob[(size_t)ln * CH + ks * 32 + t * 8];
#pragma unroll
        for (int og = 0; og < 4; og++)
            acc[og] = __builtin_amdgcn_mfma_f32_16x16x32_bf16(
                af[og], bf, acc[og], 0, 0, 0);
    }

#pragma unroll
    for (int og = 0; og < 4; og++)
#pragma unroll
        for (int r = 0; r < 4; r++) {
            int c = w * 64 + og * 16 + 4 * t + r;
            size_t idx = ((size_t)b * CH + c) * SP + s0 + ln;
            out[idx] = acc[og][r] + bp[c] + x[idx];
        }
}

// ---------------------------------------------------------------------------
extern "C" void kernel_launch(void* const* d_in, const int* in_sizes, int n_in,
                              void* d_out, int out_size, void* d_ws, size_t ws_size,
                              hipStream_t stream)
{
    const float* x     = (const float*)d_in[0];
    const float* gamma = (const float*)d_in[1];
    const float* beta  = (const float*)d_in[2];
    const float* wq = (const float*)d_in[3]; const float* bq = (const float*)d_in[4];
    const float* wk = (const float*)d_in[5]; const float* bk = (const float*)d_in[6];
    const float* wv = (const float*)d_in[7]; const float* bv = (const float*)d_in[8];
    const float* wp = (const float*)d_in[9]; const float* bp = (const float*)d_in[10];
    float* out = (float*)d_out;

    const size_t TEN = (size_t)8 * SP * HD;   // 2,097,152 elements
    char* wsb = (char*)d_ws;
    float2* part = (float2*)wsb;              // 256 float2 = 2 KB
    u16* wqb = (u16*)(wsb + 4096);
    u16* wkb = wqb + 65536;
    u16* wvb = wkb + 65536;
    u16* wpb = wvb + 65536;
    u16* qt  = wpb + 65536;
    u16* ktp = qt + TEN;
    u16* vtp = ktp + TEN;
    u16* xt  = vtp + TEN;                     // reused as Ot after qkv
    u16* ot  = xt;
    u16* opart = xt + TEN;                    // 4 splits x TEN
    float* lpart = (float*)(opart + 4 * TEN); // 4 x 8 x 4096 floats

    prep_kernel<<<dim3(1280), dim3(256), 0, stream>>>(
        x, part, wq, wk, wv, wp, wqb, wkb, wvb, wpb);
    xprep_kernel<<<dim3(64, 4, 2), dim3(256), 0, stream>>>(x, part, gamma, beta, xt);
    qkv_gemm_kernel<<<dim3(128, 6), dim3(256), 0, stream>>>(
        xt, wqb, wkb, wvb, bq, bk, bv, qt, ktp, vtp);
    attn_kernel<<<dim3(1024), dim3(256), 0, stream>>>(qt, ktp, vtp, opart, lpart);
    combine_kernel<<<dim3(8, 128), dim3(256), 0, stream>>>(opart, lpart, ot);
    proj_gemm_kernel<<<dim3(256, 2), dim3(256), 0, stream>>>(ot, wpb, bp, x, out);
}

// Round 6
// 159.839 us; speedup vs baseline: 6.6030x; 1.0947x over previous
//
#include <hip/hip_runtime.h>

#define CH 256
#define NHEAD 4
#define HD 64
#define SP 4096
#define NB 2
// softmax scale 1/8 with log2(e) folded in (we use exp2)
#define QSCALE 0.1803368801111204f

typedef __attribute__((ext_vector_type(8))) short bf16x8;   // MFMA A/B frag
typedef __attribute__((ext_vector_type(4))) float f32x4;    // MFMA C/D frag
typedef unsigned int u32;
typedef unsigned short u16;

__device__ inline u16 b16(float f) {
    u32 u = __float_as_uint(f);
    return (u16)((u + 0x8000u) >> 16);
}
__device__ inline float fexp2(float x) { return __builtin_amdgcn_exp2f(x); }

// ---------------------------------------------------------------------------
// Kernel 1: fused GN partial sums (blocks 0..255) + weight convert (256..1279).
// wq gets QSCALE folded; wp column-permuted to chan = n*64+d.
// ---------------------------------------------------------------------------
__global__ __launch_bounds__(256) void prep_kernel(
    const float* __restrict__ x, float2* __restrict__ part,
    const float* __restrict__ wq, const float* __restrict__ wk,
    const float* __restrict__ wv, const float* __restrict__ wp,
    u16* __restrict__ wqb, u16* __restrict__ wkb,
    u16* __restrict__ wvb, u16* __restrict__ wpb)
{
    int tid = threadIdx.x;
    if (blockIdx.x < 256) {
        int bgq = blockIdx.x;            // (b*32+g)*4 + qtr
        int bg = bgq >> 2, qtr = bgq & 3;
        const float4* xp = (const float4*)(x + (size_t)bg * 8 * SP) + qtr * 2048;
        float s = 0.f, ss = 0.f;
        for (int i = tid; i < 2048; i += 256) {
            float4 u = xp[i];
            s  += (u.x + u.y) + (u.z + u.w);
            ss += (u.x * u.x + u.y * u.y) + (u.z * u.z + u.w * u.w);
        }
#pragma unroll
        for (int off = 32; off > 0; off >>= 1) {
            s  += __shfl_down(s, off);
            ss += __shfl_down(ss, off);
        }
        __shared__ float ws_s[4], ws_q[4];
        int w = tid >> 6;
        if ((tid & 63) == 0) { ws_s[w] = s; ws_q[w] = ss; }
        __syncthreads();
        if (tid == 0)
            part[bgq] = make_float2(ws_s[0] + ws_s[1] + ws_s[2] + ws_s[3],
                                    ws_q[0] + ws_q[1] + ws_q[2] + ws_q[3]);
    } else {
        int idx = (blockIdx.x - 256) * 256 + tid;   // 0..262143
        int m = idx >> 16, i = idx & 65535;
        if (m == 0)      wqb[i] = b16(wq[i] * QSCALE);
        else if (m == 1) wkb[i] = b16(wk[i]);
        else if (m == 2) wvb[i] = b16(wv[i]);
        else {
            int c = i >> 8, chan = i & 255;
            int n = chan >> 6, d = chan & 63;
            wpb[i] = b16(wp[c * 256 + d * 4 + n]);
        }
    }
}

// ---------------------------------------------------------------------------
// Kernel 2: Q/K/V projection with GN fused (reads x fp32 directly).
// Per block: GN affine (from partials) -> stage X^T bf16 tile in LDS ->
// MFMA GEMM (W frags from global/L2, X frags from LDS) -> packed outputs.
// Outputs: Q bf16 [z][s][d]; K,V bf16 packed in MFMA-frag order:
//   ktp[z][tile64][g=kg*2+ds][lane][8], vtp[z][tile64][g=dg*2+ks][lane][8]
// ---------------------------------------------------------------------------
__global__ __launch_bounds__(256) void qkv_gemm_kernel(
    const float* __restrict__ x, const float2* __restrict__ part,
    const float* __restrict__ gamma, const float* __restrict__ beta,
    const u16* __restrict__ wqb, const u16* __restrict__ wkb,
    const u16* __restrict__ wvb,
    const float* __restrict__ bq, const float* __restrict__ bk,
    const float* __restrict__ bv,
    u16* __restrict__ qt, u16* __restrict__ ktp, u16* __restrict__ vtp)
{
    int zz = blockIdx.y;            // b*3 + p
    int b = zz / 3, p = zz % 3;
    const u16* W = (p == 0) ? wqb : (p == 1) ? wkb : wvb;
    const float* bias = (p == 0) ? bq : (p == 1) ? bk : bv;
    float bs = (p == 0) ? QSCALE : 1.f;
    int s0 = blockIdx.x * 32;
    int tid = threadIdx.x, w = tid >> 6, lane = tid & 63;
    int t = lane >> 4, ln = lane & 15;

    __shared__ u16 SB[10240];       // X^T tile (pitch 264), later output staging
    __shared__ float As[256], Bs[256];

    // GN affine for channel tid (partials are tiny + L2-hot)
    {
        int c = tid, bg = b * 32 + (c >> 3);
        float s = 0.f, ss = 0.f;
#pragma unroll
        for (int q = 0; q < 4; q++) { float2 pp = part[bg * 4 + q]; s += pp.x; ss += pp.y; }
        float mu = s * (1.f / 32768.f);
        float var = ss * (1.f / 32768.f) - mu * mu;
        float rs = rsqrtf(var + 1e-5f);
        float ga = gamma[c];
        As[c] = rs * ga;
        Bs[c] = beta[c] - mu * rs * ga;
    }
    __syncthreads();

    // stage Xs[s][c] = bf16(a*x+b), pitch 264 (s-tile 32 x 256 c)
    {
        int cb = tid >> 3;            // base channel lane
        int sseg = (tid & 7) * 4;
#pragma unroll
        for (int it = 0; it < 8; it++) {
            int c = it * 32 + cb;
            float4 v = *(const float4*)&x[((size_t)b * CH + c) * SP + s0 + sseg];
            float aa = As[c], bb = Bs[c];
            SB[(sseg + 0) * 264 + c] = b16(fmaf(aa, v.x, bb));
            SB[(sseg + 1) * 264 + c] = b16(fmaf(aa, v.y, bb));
            SB[(sseg + 2) * 264 + c] = b16(fmaf(aa, v.z, bb));
            SB[(sseg + 3) * 264 + c] = b16(fmaf(aa, v.w, bb));
        }
    }
    __syncthreads();

    f32x4 acc[4][2];
#pragma unroll
    for (int og = 0; og < 4; og++)
#pragma unroll
        for (int sg = 0; sg < 2; sg++)
            acc[og][sg] = (f32x4){0.f, 0.f, 0.f, 0.f};

#pragma unroll
    for (int ks = 0; ks < 8; ks++) {
        bf16x8 af[4], bfv[2];
#pragma unroll
        for (int og = 0; og < 4; og++)
            af[og] = *(const bf16x8*)&W[(size_t)(w * 64 + og * 16 + ln) * CH + ks * 32 + t * 8];
#pragma unroll
        for (int sg = 0; sg < 2; sg++)
            bfv[sg] = *(const bf16x8*)&SB[(sg * 16 + ln) * 264 + ks * 32 + t * 8];
#pragma unroll
        for (int og = 0; og < 4; og++)
#pragma unroll
            for (int sg = 0; sg < 2; sg++)
                acc[og][sg] = __builtin_amdgcn_mfma_f32_16x16x32_bf16(
                    af[og], bfv[sg], acc[og][sg], 0, 0, 0);
    }
    __syncthreads();   // SB now reused as output staging

    // C rows o = w*64+og*16+4t+r (d = w*16+og*4+t, head n = r), cols s = sg*16+ln
    if (p < 2) {
#pragma unroll
        for (int og = 0; og < 4; og++)
#pragma unroll
            for (int sg = 0; sg < 2; sg++)
#pragma unroll
                for (int r = 0; r < 4; r++) {
                    int o = w * 64 + og * 16 + 4 * t + r;
                    SB[(r * 32 + sg * 16 + ln) * 72 + (w * 16 + og * 4 + t)] =
                        b16(acc[og][sg][r] + bias[o] * bs);
                }
        __syncthreads();
        if (p == 0) {
#pragma unroll
            for (int it = 0; it < 4; it++) {
                int idx = it * 256 + tid;
                int o8 = idx & 7, sl = (idx >> 3) & 31, n = idx >> 8;
                *(uint4*)&qt[((size_t)(b * 4 + n) * SP + s0 + sl) * HD + o8 * 8] =
                    *(const uint4*)&SB[(n * 32 + sl) * 72 + o8 * 8];
            }
        } else {
#pragma unroll
            for (int it = 0; it < 4; it++) {
                int idx = it * 256 + tid;
                int o8 = idx & 7, sl = (idx >> 3) & 31, n = idx >> 8;
                int key = s0 + sl;
                int g = ((key >> 4) & 3) * 2 + (o8 >> 2);
                int lp = (key & 15) + 16 * (o8 & 3);
                *(uint4*)&ktp[(size_t)(b * 4 + n) * SP * HD +
                              (size_t)(key >> 6) * 4096 + g * 512 + lp * 8] =
                    *(const uint4*)&SB[(n * 32 + sl) * 72 + o8 * 8];
            }
        }
    } else {
#pragma unroll
        for (int og = 0; og < 4; og++)
#pragma unroll
            for (int sg = 0; sg < 2; sg++)
#pragma unroll
                for (int r = 0; r < 4; r++) {
                    int o = w * 64 + og * 16 + 4 * t + r;
                    SB[(r * 64 + w * 16 + og * 4 + t) * 40 + sg * 16 + ln] =
                        b16(acc[og][sg][r] + bias[o]);
                }
        __syncthreads();
#pragma unroll
        for (int it = 0; it < 4; it++) {
            int idx = it * 256 + tid;
            int so8 = idx & 3, d = (idx >> 2) & 63, n = idx >> 8;
            int key = s0 + so8 * 8;
            int g = ((d >> 4) & 3) * 2 + ((key >> 5) & 1);
            int lp = (d & 15) + 16 * ((key >> 3) & 3);
            *(uint4*)&vtp[(size_t)(b * 4 + n) * SP * HD +
                          (size_t)(key >> 6) * 4096 + g * 512 + lp * 8] =
                *(const uint4*)&SB[(n * 64 + d) * 40 + so8 * 8];
        }
    }
}

// ---------------------------------------------------------------------------
// Kernel 3: MFMA flash attention — NO BARRIERS. q=128/block (32/wave, qg=2),
// k-split=4, grid 1024, z = bx&7 = XCD (K/V L2-local, 1 MB/XCD).
// K/V frags loaded DIRECT from frag-packed global (L1/L2 shared across the
// block's 4 waves); K prefetched one tile ahead. LDS = wave-private P
// round-trip only (16 KB). Epilogue packs O via the dead P region -> b128.
// ---------------------------------------------------------------------------
__global__ __launch_bounds__(256, 3) void attn_kernel(
    const u16* __restrict__ qtb, const u16* __restrict__ ktp,
    const u16* __restrict__ vtp, u16* __restrict__ opart,
    float* __restrict__ lpart)
{
    int bx = blockIdx.x;
    int z = bx & 7, qt_i = (bx >> 3) & 31, sp = bx >> 8;
    int sq0 = qt_i * 128;
    int tile0 = sp * 16;
    const u16* qz = qtb + (size_t)z * SP * HD;
    const u16* kz = ktp + (size_t)z * SP * HD;
    const u16* vz = vtp + (size_t)z * SP * HD;

    int tid = threadIdx.x, w = tid >> 6, l = tid & 63;
    int t = l >> 4, ln = l & 15;

    __shared__ __align__(16) u32 Pb[4][2][512];   // 16 KB, wave-private

    // Q B-frags [qg][ds] (scale folded into wq/bq)
    bf16x8 qf[2][2];
#pragma unroll
    for (int qg = 0; qg < 2; qg++)
#pragma unroll
        for (int ds = 0; ds < 2; ds++)
            qf[qg][ds] = *(const bf16x8*)&qz[
                (size_t)(sq0 + w * 32 + qg * 16 + ln) * HD + ds * 32 + t * 8];

    // preload K tile 0 (frag-packed: one b128 per group, all 8 groups)
    bf16x8 kf[8], vf[8];
#pragma unroll
    for (int g = 0; g < 8; g++)
        kf[g] = *(const bf16x8*)&kz[(size_t)tile0 * 4096 + g * 512 + l * 8];

    float lsum[2] = {0.f, 0.f};
    f32x4 oacc[2][4];
#pragma unroll
    for (int qg = 0; qg < 2; qg++)
#pragma unroll
        for (int dg = 0; dg < 4; dg++)
            oacc[qg][dg] = (f32x4){0.f, 0.f, 0.f, 0.f};

    const f32x4 z4 = {0.f, 0.f, 0.f, 0.f};
    f32x4 sa[2][4];

    auto ep = [&](int qg) {   // exp2 + pack + wave-private P store
#pragma unroll
        for (int kg = 0; kg < 4; kg++) {
            float e0 = fexp2(sa[qg][kg][0]);
            float e1 = fexp2(sa[qg][kg][1]);
            float e2 = fexp2(sa[qg][kg][2]);
            float e3 = fexp2(sa[qg][kg][3]);
            lsum[qg] += (e0 + e1) + (e2 + e3);
            u32 p0 = __builtin_amdgcn_perm(__float_as_uint(e1), __float_as_uint(e0), 0x07060302u);
            u32 p1 = __builtin_amdgcn_perm(__float_as_uint(e3), __float_as_uint(e2), 0x07060302u);
            int Lt = ln + 16 * (2 * (kg & 1) + (t >> 1));
            int ksg = kg >> 1;
            *(uint2*)&Pb[w][qg][(ksg * 64 + Lt) * 4 + 2 * (t & 1)] =
                make_uint2(p0, p1);
        }
    };

    for (int kti = 0; kti < 16; kti++) {
        size_t tb = (size_t)(tile0 + kti) * 4096;

        // V frag loads for current tile (consumed after exp -> latency hidden)
#pragma unroll
        for (int g = 0; g < 8; g++)
            vf[g] = *(const bf16x8*)&vz[tb + g * 512 + l * 8];

        // QK^T (sa zero-init via z4 on first K-half)
#pragma unroll
        for (int kg = 0; kg < 4; kg++) {
#pragma unroll
            for (int qg = 0; qg < 2; qg++)
                sa[qg][kg] = __builtin_amdgcn_mfma_f32_16x16x32_bf16(
                    kf[kg * 2 + 0], qf[qg][0], z4, 0, 0, 0);
        }
#pragma unroll
        for (int kg = 0; kg < 4; kg++) {
#pragma unroll
            for (int qg = 0; qg < 2; qg++)
                sa[qg][kg] = __builtin_amdgcn_mfma_f32_16x16x32_bf16(
                    kf[kg * 2 + 1], qf[qg][1], sa[qg][kg], 0, 0, 0);
        }

        // prefetch next K tile (overlaps exp + PV)
        if (kti < 15) {
            size_t nb = tb + 4096;
#pragma unroll
            for (int g = 0; g < 8; g++)
                kf[g] = *(const bf16x8*)&kz[nb + g * 512 + l * 8];
        }

        // softmax + PV, pipelined over qg (Pb wave-private, in-wave DS order)
        ep(0);
#pragma unroll
        for (int qg = 0; qg < 2; qg++) {
            if (qg == 0) ep(1);
            bf16x8 pf[2];
#pragma unroll
            for (int ksg = 0; ksg < 2; ksg++)
                pf[ksg] = *(const bf16x8*)&Pb[w][qg][(ksg * 64 + l) * 4];
#pragma unroll
            for (int ksg = 0; ksg < 2; ksg++)
#pragma unroll
                for (int dg = 0; dg < 4; dg++)
                    oacc[qg][dg] = __builtin_amdgcn_mfma_f32_16x16x32_bf16(
                        pf[ksg], vf[dg * 2 + ksg], oacc[qg][dg], 0, 0, 0);
        }
    }

    // l reduction (once)
#pragma unroll
    for (int qg = 0; qg < 2; qg++) {
        lsum[qg] += __shfl_xor(lsum[qg], 16);
        lsum[qg] += __shfl_xor(lsum[qg], 32);
    }

    // epilogue: transpose O through the (dead) wave-private Pb region
    size_t obase = (size_t)(sp * 8 + z) * SP;
    u16* po = (u16*)&Pb[w][0][0];     // 2048 u16 = 32 q x 64 d
#pragma unroll
    for (int qg = 0; qg < 2; qg++)
#pragma unroll
        for (int dg = 0; dg < 4; dg++)
#pragma unroll
            for (int r = 0; r < 4; r++)
                po[(qg * 16 + 4 * t + r) * 64 + dg * 16 + ln] = b16(oacc[qg][dg][r]);
#pragma unroll
    for (int i = 0; i < 4; i++) {
        int f = i * 512 + l * 8;
        int qloc = f >> 6, d0 = f & 63;
        uint4 v = *(const uint4*)&po[f];
        *(uint4*)&opart[(obase + sq0 + w * 32 + qloc) * HD + d0] = v;
    }
    if (t == 0)
#pragma unroll
        for (int qg = 0; qg < 2; qg++)
            lpart[obase + sq0 + w * 32 + qg * 16 + ln] = lsum[qg];
}

// ---------------------------------------------------------------------------
// Kernel 4: output projection + residual, k-split combine fused into the
// B-frag build: B[s][chan] = (sum_sp opart)/(sum_sp l). s-tile 16, 512 blocks.
// ---------------------------------------------------------------------------
__global__ __launch_bounds__(256) void proj_gemm_kernel(
    const u16* __restrict__ opart, const float* __restrict__ lpart,
    const u16* __restrict__ wpb, const float* __restrict__ bp,
    const float* __restrict__ x, float* __restrict__ out)
{
    int b = blockIdx.y;
    int s0 = blockIdx.x * 16;
    int tid = threadIdx.x, w = tid >> 6, lane = tid & 63;
    int t = lane >> 4, ln = lane & 15;

    // per-lane 1/l for each head n (q = s0 + ln)
    float linv[4];
#pragma unroll
    for (int n = 0; n < 4; n++) {
        float s = 0.f;
#pragma unroll
        for (int sp = 0; sp < 4; sp++)
            s += lpart[(size_t)(sp * 8 + b * 4 + n) * SP + s0 + ln];
        linv[n] = 1.f / s;
    }

    f32x4 acc[4];
#pragma unroll
    for (int og = 0; og < 4; og++)
        acc[og] = (f32x4){0.f, 0.f, 0.f, 0.f};

#pragma unroll
    for (int ks = 0; ks < 8; ks++) {
        bf16x8 af[4];
#pragma unroll
        for (int og = 0; og < 4; og++)
            af[og] = *(const bf16x8*)&wpb[(size_t)(w * 64 + og * 16 + ln) * CH + ks * 32 + t * 8];

        // combine 4 k-split parts into the B-frag
        int n = ks >> 1;
        int d0 = (ks & 1) * 32 + t * 8;
        u32 ov[4][4];
#pragma unroll
        for (int sp = 0; sp < 4; sp++) {
            uint4 o4 = *(const uint4*)&opart[
                ((size_t)(sp * 8 + b * 4 + n) * SP + s0 + ln) * HD + d0];
            ov[sp][0] = o4.x; ov[sp][1] = o4.y; ov[sp][2] = o4.z; ov[sp][3] = o4.w;
        }
        float inv = linv[n];
        union { u32 u[4]; bf16x8 v; } bu;
#pragma unroll
        for (int i = 0; i < 4; i++) {
            float lo = 0.f, hi = 0.f;
#pragma unroll
            for (int sp = 0; sp < 4; sp++) {
                lo += __uint_as_float(ov[sp][i] << 16);
                hi += __uint_as_float(ov[sp][i] & 0xffff0000u);
            }
            u16 rl = b16(lo * inv), rh = b16(hi * inv);
            bu.u[i] = ((u32)rh << 16) | rl;
        }
#pragma unroll
        for (int og = 0; og < 4; og++)
            acc[og] = __builtin_amdgcn_mfma_f32_16x16x32_bf16(
                af[og], bu.v, acc[og], 0, 0, 0);
    }

#pragma unroll
    for (int og = 0; og < 4; og++)
#pragma unroll
        for (int r = 0; r < 4; r++) {
            int c = w * 64 + og * 16 + 4 * t + r;
            size_t idx = ((size_t)b * CH + c) * SP + s0 + ln;
            out[idx] = acc[og][r] + bp[c] + x[idx];
        }
}

// ---------------------------------------------------------------------------
extern "C" void kernel_launch(void* const* d_in, const int* in_sizes, int n_in,
                              void* d_out, int out_size, void* d_ws, size_t ws_size,
                              hipStream_t stream)
{
    const float* x     = (const float*)d_in[0];
    const float* gamma = (const float*)d_in[1];
    const float* beta  = (const float*)d_in[2];
    const float* wq = (const float*)d_in[3]; const float* bq = (const float*)d_in[4];
    const float* wk = (const float*)d_in[5]; const float* bk = (const float*)d_in[6];
    const float* wv = (const float*)d_in[7]; const float* bv = (const float*)d_in[8];
    const float* wp = (const float*)d_in[9]; const float* bp = (const float*)d_in[10];
    float* out = (float*)d_out;

    const size_t TEN = (size_t)8 * SP * HD;   // 2,097,152 elements
    char* wsb = (char*)d_ws;
    float2* part = (float2*)wsb;              // 256 float2 = 2 KB
    u16* wqb = (u16*)(wsb + 4096);
    u16* wkb = wqb + 65536;
    u16* wvb = wkb + 65536;
    u16* wpb = wvb + 65536;
    u16* qt  = wpb + 65536;
    u16* ktp = qt + TEN;
    u16* vtp = ktp + TEN;
    u16* opart = vtp + TEN;                   // 4 splits x TEN
    float* lpart = (float*)(opart + 4 * TEN); // 4 x 8 x 4096 floats

    prep_kernel<<<dim3(1280), dim3(256), 0, stream>>>(
        x, part, wq, wk, wv, wp, wqb, wkb, wvb, wpb);
    qkv_gemm_kernel<<<dim3(128, 6), dim3(256), 0, stream>>>(
        x, part, gamma, beta, wqb, wkb, wvb, bq, bk, bv, qt, ktp, vtp);
    attn_kernel<<<dim3(1024), dim3(256), 0, stream>>>(qt, ktp, vtp, opart, lpart);
    proj_gemm_kernel<<<dim3(256, 2), dim3(256), 0, stream>>>(
        opart, lpart, wpb, bp, x, out);
}